// Round 9
// baseline (521.322 us; speedup 1.0000x reference)
//
#include <hip/hip_runtime.h>
#include <hip/hip_bf16.h>
#include <math.h>

#define TT 2048
#define DD 768

typedef __bf16 bf16x8 __attribute__((ext_vector_type(8)));
typedef float f32x4 __attribute__((ext_vector_type(4)));

__device__ __forceinline__ void gload16(const void* g, void* l) {
    __builtin_amdgcn_global_load_lds(
        (const __attribute__((address_space(1))) unsigned int*)g,
        (__attribute__((address_space(3))) unsigned int*)l, 16, 0, 0);
}

__device__ __forceinline__ bf16x8 zero8() {
    bf16x8 v;
    #pragma unroll
    for (int j = 0; j < 8; ++j) v[j] = (__bf16)0.0f;
    return v;
}

// ---------------------------------------------------------------- LayerNorm (fp32 in -> bf16 out)
__global__ __launch_bounds__(256) void ln_kernel(const float* __restrict__ in,
    const float* __restrict__ g, const float* __restrict__ b,
    __hip_bfloat16* __restrict__ out)
{
    const int t = blockIdx.x;
    const int tid = threadIdx.x;
    const float* row = in + (size_t)t * DD;
    float x0 = row[tid], x1 = row[tid + 256], x2 = row[tid + 512];
    float s = x0 + x1 + x2;
    float q = x0 * x0 + x1 * x1 + x2 * x2;
    #pragma unroll
    for (int m = 1; m < 64; m <<= 1) {
        s += __shfl_xor(s, m);
        q += __shfl_xor(q, m);
    }
    __shared__ float ssum[4], sqsum[4];
    const int w = tid >> 6;
    if ((tid & 63) == 0) { ssum[w] = s; sqsum[w] = q; }
    __syncthreads();
    s = ssum[0] + ssum[1] + ssum[2] + ssum[3];
    q = sqsum[0] + sqsum[1] + sqsum[2] + sqsum[3];
    const float mean = s * (1.0f / DD);
    const float var = q * (1.0f / DD) - mean * mean;
    const float rs = rsqrtf(var + 1e-5f);
    __hip_bfloat16* orow = out + (size_t)t * DD;
    orow[tid]       = __float2bfloat16((x0 - mean) * rs * g[tid]       + b[tid]);
    orow[tid + 256] = __float2bfloat16((x1 - mean) * rs * g[tid + 256] + b[tid + 256]);
    orow[tid + 512] = __float2bfloat16((x2 - mean) * rs * g[tid + 512] + b[tid + 512]);
}

// ------------------------------------------- transpose + cast: fp32 [K,N] -> bf16 [N,K]
__global__ __launch_bounds__(256) void castT_kernel(const float* __restrict__ in,
    __hip_bfloat16* __restrict__ out, int K, int N)
{
    __shared__ float t[32][33];
    const int n0 = blockIdx.x << 5, k0 = blockIdx.y << 5;
    const int tx = threadIdx.x & 31, ty = threadIdx.x >> 5;
    #pragma unroll
    for (int i = 0; i < 32; i += 8)
        t[ty + i][tx] = in[(size_t)(k0 + ty + i) * N + n0 + tx];
    __syncthreads();
    #pragma unroll
    for (int i = 0; i < 32; i += 8)
        out[(size_t)(n0 + ty + i) * K + k0 + tx] = __float2bfloat16(t[tx][ty + i]);
}

// ---------------------------------------------------------------- MFMA GEMM
// C[M,N] = A[M,K](bf16) @ Bt[N,K]^T(bf16) + bias(fp32)
// epi: 0=none, 1=gelu, 2=+resid(fp32) ; omode: 1=bf16 out, else fp32 out
__device__ __forceinline__ float gelu_f(float x) {
    float u = 0.7978845608028654f * (x + 0.044715f * x * x * x);
    return 0.5f * x * (1.0f + tanhf(u));
}

__global__ __launch_bounds__(256) void mgemm_kernel(
    const __hip_bfloat16* __restrict__ A, const __hip_bfloat16* __restrict__ Bt,
    const float* __restrict__ bias, const float* __restrict__ resid,
    void* __restrict__ Cout, int M, int N, int K, int epi, int omode)
{
    __shared__ __hip_bfloat16 As[128 * 32];
    __shared__ __hip_bfloat16 Bs[128 * 32];
    const int tid = threadIdx.x;
    const int lane = tid & 63, wv = tid >> 6;
    const int wm = wv >> 1, wn = wv & 1;
    const int rowBase = blockIdx.y << 7, colBase = blockIdx.x << 7;

    f32x4 acc[4][4];
    #pragma unroll
    for (int i = 0; i < 4; ++i)
        #pragma unroll
        for (int j = 0; j < 4; ++j) acc[i][j] = (f32x4){0.f, 0.f, 0.f, 0.f};

    const int lr = lane >> 2;
    const int pc = lane & 3;
    const int r0 = wv << 5;
    const int lrow0 = r0 + lr, lrow1 = r0 + 16 + lr;
    const int c0 = (pc ^ ((lrow0 >> 1) & 3)) << 3;
    const int c1 = (pc ^ ((lrow1 >> 1) & 3)) << 3;
    const int m = lane & 15, q = lane >> 4;

    for (int k0 = 0; k0 < K; k0 += 32) {
        __syncthreads();
        gload16(A  + (size_t)(rowBase + lrow0) * K + k0 + c0, &As[(size_t)r0 * 32]);
        gload16(A  + (size_t)(rowBase + lrow1) * K + k0 + c1, &As[(size_t)(r0 + 16) * 32]);
        gload16(Bt + (size_t)(colBase + lrow0) * K + k0 + c0, &Bs[(size_t)r0 * 32]);
        gload16(Bt + (size_t)(colBase + lrow1) * K + k0 + c1, &Bs[(size_t)(r0 + 16) * 32]);
        __syncthreads();

        bf16x8 af[4], bfr[4];
        #pragma unroll
        for (int i = 0; i < 4; ++i) {
            int row = (wm << 6) + (i << 4) + m;
            int pos = q ^ ((row >> 1) & 3);
            af[i] = *(const bf16x8*)&As[row * 32 + (pos << 3)];
        }
        #pragma unroll
        for (int j = 0; j < 4; ++j) {
            int row = (wn << 6) + (j << 4) + m;
            int pos = q ^ ((row >> 1) & 3);
            bfr[j] = *(const bf16x8*)&Bs[row * 32 + (pos << 3)];
        }
        #pragma unroll
        for (int i = 0; i < 4; ++i)
            #pragma unroll
            for (int j = 0; j < 4; ++j)
                acc[i][j] = __builtin_amdgcn_mfma_f32_16x16x32_bf16(af[i], bfr[j], acc[i][j], 0, 0, 0);
    }

    #pragma unroll
    for (int j = 0; j < 4; ++j) {
        const int col = colBase + (wn << 6) + (j << 4) + m;
        const float bj = bias[col];
        #pragma unroll
        for (int i = 0; i < 4; ++i) {
            #pragma unroll
            for (int r = 0; r < 4; ++r) {
                const int row = rowBase + (wm << 6) + (i << 4) + (q << 2) + r;
                float v = acc[i][j][r] + bj;
                if (epi == 1) v = gelu_f(v);
                else if (epi == 2) v += resid[(size_t)row * N + col];
                if (omode == 1) ((__hip_bfloat16*)Cout)[(size_t)row * N + col] = __float2bfloat16(v);
                else ((float*)Cout)[(size_t)row * N + col] = v;
            }
        }
    }
}

// ------------------------------------------------- small projections + exterior
__device__ __forceinline__ void exterior6(const float* a, const float* b, float* L) {
    L[0] = a[0] * b[1] - a[1] * b[0];
    L[1] = a[0] * b[2] - a[2] * b[0];
    L[2] = a[0] * b[3] - a[3] * b[0];
    L[3] = a[1] * b[2] - a[2] * b[1];
    L[4] = a[1] * b[3] - a[3] * b[1];
    L[5] = a[2] * b[3] - a[3] * b[2];
    float n = sqrtf(L[0]*L[0] + L[1]*L[1] + L[2]*L[2] + L[3]*L[3] + L[4]*L[4] + L[5]*L[5]);
    float inv = 1.f / fmaxf(n, 1e-12f);
    #pragma unroll
    for (int p = 0; p < 6; ++p) L[p] *= inv;
}

// outputs: rlb/jwb bf16 [12][2048][8] (6 real + 2 zero pad), gate fp32 [2048]
__global__ __launch_bounds__(256) void smallproj_kernel(
    const __hip_bfloat16* __restrict__ ln1,
    const float* __restrict__ w1w, const float* __restrict__ w2w,
    const float* __restrict__ w1r, const float* __restrict__ w2r,
    const float* __restrict__ gw, const float* __restrict__ gb,
    __hip_bfloat16* __restrict__ rlb, __hip_bfloat16* __restrict__ jwb,
    float* __restrict__ gate)
{
    const int t = blockIdx.x;
    const int tid = threadIdx.x;
    __shared__ float xc[768], xp[768], res[204];
    const __hip_bfloat16* cur = ln1 + (size_t)t * DD;
    #pragma unroll
    for (int i = 0; i < 3; ++i) {
        int idx = tid + (i << 8);
        xc[idx] = __bfloat162float(cur[idx]);
        xp[idx] = (t > 0) ? __bfloat162float(cur[idx - DD]) : 0.f;
    }
    __syncthreads();
    if (tid < 204) {
        const float* wsel; const float* xv; int col, stride;
        if (tid < 48)       { wsel = w2w; xv = xc; col = tid;       stride = 48; }
        else if (tid < 96)  { wsel = w1w; xv = xp; col = tid - 48;  stride = 48; }
        else if (tid < 144) { wsel = w1r; xv = xc; col = tid - 96;  stride = 48; }
        else if (tid < 192) { wsel = w2r; xv = xc; col = tid - 144; stride = 48; }
        else                { wsel = gw;  xv = xc; col = tid - 192; stride = 12; }
        float s = 0.f;
        for (int k = 0; k < 768; ++k) s += xv[k] * wsel[(size_t)k * stride + col];
        if (tid >= 192) s += gb[col];
        res[tid] = s;
    }
    __syncthreads();
    if (tid < 12) {
        const int h = tid;
        float a[4], b[4], L[6];
        // write lines: exterior(w1(x_prev), w2(x)) then J6 = [L5,-L4,L3,L2,-L1,L0]
        #pragma unroll
        for (int i = 0; i < 4; ++i) { a[i] = res[48 + h * 4 + i]; b[i] = res[h * 4 + i]; }
        exterior6(a, b, L);
        __hip_bfloat16* jwp = jwb + (size_t)h * 16384 + t * 8;
        jwp[0] = __float2bfloat16( L[5]); jwp[1] = __float2bfloat16(-L[4]);
        jwp[2] = __float2bfloat16( L[3]); jwp[3] = __float2bfloat16( L[2]);
        jwp[4] = __float2bfloat16(-L[1]); jwp[5] = __float2bfloat16( L[0]);
        jwp[6] = __float2bfloat16(0.f);   jwp[7] = __float2bfloat16(0.f);
        // read lines: exterior(r1, r2)
        #pragma unroll
        for (int i = 0; i < 4; ++i) { a[i] = res[96 + h * 4 + i]; b[i] = res[144 + h * 4 + i]; }
        exterior6(a, b, L);
        __hip_bfloat16* rlp = rlb + (size_t)h * 16384 + t * 8;
        #pragma unroll
        for (int p = 0; p < 6; ++p) rlp[p] = __float2bfloat16(L[p]);
        rlp[6] = __float2bfloat16(0.f); rlp[7] = __float2bfloat16(0.f);
    }
    if (tid == 0) {
        float g = 0.f;
        #pragma unroll
        for (int i = 0; i < 12; ++i) g += 1.f / (1.f + __expf(-res[192 + i]));
        gate[t] = g * (1.f / 12.f);
    }
}

// ------------------------------------------- per-head transpose: V/GV -> VT[h][64][2048]
__global__ __launch_bounds__(256) void vt_kernel(
    const __hip_bfloat16* __restrict__ qkvB, const __hip_bfloat16* __restrict__ geovB,
    __hip_bfloat16* __restrict__ VT, __hip_bfloat16* __restrict__ GVT)
{
    __shared__ __hip_bfloat16 tile[64][72];
    const int s0 = blockIdx.x << 6, h = blockIdx.y;
    const bool isGV = (blockIdx.z != 0);
    const __hip_bfloat16* src = isGV ? (geovB + h * 64) : (qkvB + 1536 + h * 64);
    const int stride = isGV ? 768 : 2304;
    __hip_bfloat16* dst = (isGV ? GVT : VT) + (size_t)h * 131072;
    const int tid = threadIdx.x;
    const int r = tid >> 2, c = (tid & 3) << 3;
    *(bf16x8*)&tile[r][c]      = *(const bf16x8*)&src[(size_t)(s0 + r) * stride + c];
    *(bf16x8*)&tile[r][c + 32] = *(const bf16x8*)&src[(size_t)(s0 + r) * stride + c + 32];
    __syncthreads();
    __hip_bfloat16 tmp[8];
    #pragma unroll
    for (int j = 0; j < 8; ++j) tmp[j] = tile[c + j][r];
    *(bf16x8*)&dst[(size_t)r * 2048 + s0 + c] = *(const bf16x8*)tmp;
    #pragma unroll
    for (int j = 0; j < 8; ++j) tmp[j] = tile[c + 32 + j][r];
    *(bf16x8*)&dst[(size_t)r * 2048 + s0 + c + 32] = *(const bf16x8*)tmp;
}

// ---------------------------------------------------------------- MFMA dual-path flash attention
// One wave (64-thr block) per (16-row q-tile, head, K-chunk). Barrier-free:
// K/V/GV/JW B-fragments read directly from global (L2-resident); only LDS use
// is the wave-private P C->A round-trip (4.6 KB).
// job j (reversed for longest-first): j<128 -> qi=j, chunk0; j>=128 -> qi=j-64, chunk1.
// qi<64: single chunk writes comb. qi>=64: both chunks write partials+stats.
__global__ __launch_bounds__(64) void mattn_kernel(
    const __hip_bfloat16* __restrict__ qkvB, const __hip_bfloat16* __restrict__ VT,
    const __hip_bfloat16* __restrict__ GVT, const __hip_bfloat16* __restrict__ rlb,
    const __hip_bfloat16* __restrict__ jwb, const float* __restrict__ gate,
    const float* __restrict__ inc_scale, __hip_bfloat16* __restrict__ comb,
    __hip_bfloat16* __restrict__ Opart, float* __restrict__ stats)
{
    __shared__ __bf16 Ps[16][72];
    __shared__ __bf16 Pg[16][72];

    const int j = 191 - blockIdx.x;
    const int h = blockIdx.y;
    const int qi = (j < 128) ? j : (j - 64);
    const int chunk = (j < 128) ? 0 : 1;
    const int q0 = qi << 4;
    const int nk = (qi >> 2) + 1;            // k-tiles needed
    const int ktb = chunk << 4;
    const int kte = (chunk == 0) ? ((nk - 1 < 15) ? nk - 1 : 15) : (nk - 1);
    const int dtile = qi >> 2;               // diagonal k-tile
    const int lane = threadIdx.x & 63;
    const int n = lane & 15, quad = lane >> 4;

    // Q fragments (A-layout: lane m=n holds row q0+n, k=quad*8+j)
    const int qrow = q0 + n;
    const size_t qb = (size_t)qrow * 2304 + h * 64;
    bf16x8 af0 = *(const bf16x8*)&qkvB[qb + (quad << 3)];
    bf16x8 af1 = *(const bf16x8*)&qkvB[qb + 32 + (quad << 3)];
    bf16x8 rlA = zero8();
    if (quad == 0) rlA = *(const bf16x8*)&rlb[(size_t)h * 16384 + (size_t)qrow * 8];
    const float isc = inc_scale[h];
    const __hip_bfloat16* Kb = qkvB + 768 + h * 64;
    const __hip_bfloat16* Vb = VT + (size_t)h * 131072;
    const __hip_bfloat16* Gb = GVT + (size_t)h * 131072;
    const __hip_bfloat16* Jb = jwb + (size_t)h * 16384;

    f32x4 Os[4], Og[4];
    float m_s[4], l_s[4], m_g[4], l_g[4];
    #pragma unroll
    for (int r = 0; r < 4; ++r) {
        m_s[r] = -1e30f; l_s[r] = 0.f; m_g[r] = -1e30f; l_g[r] = 0.f;
        Os[r] = (f32x4){0.f, 0.f, 0.f, 0.f};
        Og[r] = (f32x4){0.f, 0.f, 0.f, 0.f};
    }

    for (int kt = ktb; kt <= kte; ++kt) {
        const int k0 = kt << 6;

        // ---- S = QK^T (std) and RL·JW (geo); B-frags direct from global
        f32x4 Ss[4], Sg[4];
        #pragma unroll
        for (int t = 0; t < 4; ++t) {
            Ss[t] = (f32x4){0.f, 0.f, 0.f, 0.f};
            Sg[t] = (f32x4){0.f, 0.f, 0.f, 0.f};
        }
        #pragma unroll
        for (int t = 0; t < 4; ++t) {
            const size_t kr = (size_t)(k0 + (t << 4) + n) * 2304;
            bf16x8 kb0 = *(const bf16x8*)&Kb[kr + (quad << 3)];
            bf16x8 kb1 = *(const bf16x8*)&Kb[kr + 32 + (quad << 3)];
            Ss[t] = __builtin_amdgcn_mfma_f32_16x16x32_bf16(af0, kb0, Ss[t], 0, 0, 0);
            Ss[t] = __builtin_amdgcn_mfma_f32_16x16x32_bf16(af1, kb1, Ss[t], 0, 0, 0);
            bf16x8 jb = zero8();
            if (quad == 0) jb = *(const bf16x8*)&Jb[(size_t)(k0 + (t << 4) + n) * 8];
            Sg[t] = __builtin_amdgcn_mfma_f32_16x16x32_bf16(rlA, jb, Sg[t], 0, 0, 0);
        }
        // scale + causal mask (diagonal k-tile only)
        #pragma unroll
        for (int t = 0; t < 4; ++t) {
            #pragma unroll
            for (int r = 0; r < 4; ++r) { Ss[t][r] *= 0.125f; Sg[t][r] *= isc; }
        }
        if (kt == dtile) {
            #pragma unroll
            for (int t = 0; t < 4; ++t) {
                const int sg = k0 + (t << 4) + n;
                #pragma unroll
                for (int r = 0; r < 4; ++r) {
                    const int qg = q0 + (quad << 2) + r;
                    if (sg > qg) { Ss[t][r] = -1e30f; Sg[t][r] = -1e30f; }
                }
            }
        }

        // ---- online softmax, both paths; Ss/Sg -> probabilities
        #pragma unroll
        for (int r = 0; r < 4; ++r) {
            float mx = fmaxf(fmaxf(Ss[0][r], Ss[1][r]), fmaxf(Ss[2][r], Ss[3][r]));
            #pragma unroll
            for (int mk = 1; mk < 16; mk <<= 1) mx = fmaxf(mx, __shfl_xor(mx, mk));
            float mnew = fmaxf(m_s[r], mx);
            float alpha = __expf(m_s[r] - mnew);
            m_s[r] = mnew;
            float sm = 0.f;
            #pragma unroll
            for (int t = 0; t < 4; ++t) { Ss[t][r] = __expf(Ss[t][r] - mnew); sm += Ss[t][r]; }
            #pragma unroll
            for (int mk = 1; mk < 16; mk <<= 1) sm += __shfl_xor(sm, mk);
            l_s[r] = l_s[r] * alpha + sm;
            #pragma unroll
            for (int t = 0; t < 4; ++t) Os[t][r] *= alpha;

            float mxg = fmaxf(fmaxf(Sg[0][r], Sg[1][r]), fmaxf(Sg[2][r], Sg[3][r]));
            #pragma unroll
            for (int mk = 1; mk < 16; mk <<= 1) mxg = fmaxf(mxg, __shfl_xor(mxg, mk));
            float mnewg = fmaxf(m_g[r], mxg);
            float alphag = __expf(m_g[r] - mnewg);
            m_g[r] = mnewg;
            float smg = 0.f;
            #pragma unroll
            for (int t = 0; t < 4; ++t) { Sg[t][r] = __expf(Sg[t][r] - mnewg); smg += Sg[t][r]; }
            #pragma unroll
            for (int mk = 1; mk < 16; mk <<= 1) smg += __shfl_xor(smg, mk);
            l_g[r] = l_g[r] * alphag + smg;
            #pragma unroll
            for (int t = 0; t < 4; ++t) Og[t][r] *= alphag;
        }

        // ---- P -> LDS (C-layout rows quad*4+r), fence, A-layout reads
        #pragma unroll
        for (int t = 0; t < 4; ++t) {
            #pragma unroll
            for (int r = 0; r < 4; ++r) {
                Ps[(quad << 2) + r][(t << 4) + n] = (__bf16)Ss[t][r];
                Pg[(quad << 2) + r][(t << 4) + n] = (__bf16)Sg[t][r];
            }
        }
        __syncthreads();   // single-wave block: compiles to cheap waitcnt+barrier

        // ---- PV both paths: B-frags direct from global (VT layout)
        #pragma unroll
        for (int st = 0; st < 2; ++st) {
            bf16x8 ap = *(const bf16x8*)&Ps[n][(st << 5) + (quad << 3)];
            bf16x8 gp = *(const bf16x8*)&Pg[n][(st << 5) + (quad << 3)];
            #pragma unroll
            for (int dt = 0; dt < 4; ++dt) {
                const size_t vr = (size_t)((dt << 4) + n) * 2048 + k0 + (st << 5) + (quad << 3);
                bf16x8 vb2 = *(const bf16x8*)&Vb[vr];
                bf16x8 gb2 = *(const bf16x8*)&Gb[vr];
                Os[dt] = __builtin_amdgcn_mfma_f32_16x16x32_bf16(ap, vb2, Os[dt], 0, 0, 0);
                Og[dt] = __builtin_amdgcn_mfma_f32_16x16x32_bf16(gp, gb2, Og[dt], 0, 0, 0);
            }
        }
        __syncthreads();   // P reads done before next iteration overwrites
    }

    if (qi < 64) {
        // ---- direct epilogue
        #pragma unroll
        for (int r = 0; r < 4; ++r) {
            const int row = q0 + (quad << 2) + r;
            const float g = gate[row];
            const float invs = (1.f - g) / l_s[r], invg = g / l_g[r];
            #pragma unroll
            for (int dt = 0; dt < 4; ++dt) {
                float val = Os[dt][r] * invs + Og[dt][r] * invg;
                comb[(size_t)row * DD + h * 64 + (dt << 4) + n] = __float2bfloat16(val);
            }
        }
    } else {
        // ---- partial epilogue: unnormalized O (bf16) + per-row stats
        const int slot = ((h << 6) | (qi - 64)) * 2 + chunk;
        __hip_bfloat16* op = Opart + (size_t)slot * 2048;    // [row16][path2*col64]
        float* st = stats + slot * 64;                        // [row16][4]
        #pragma unroll
        for (int r = 0; r < 4; ++r) {
            const int rloc = (quad << 2) + r;
            #pragma unroll
            for (int dt = 0; dt < 4; ++dt) {
                const int col = (dt << 4) + n;
                op[rloc * 128 + col]      = __float2bfloat16(Os[dt][r]);
                op[rloc * 128 + 64 + col] = __float2bfloat16(Og[dt][r]);
            }
            if (n == 0) {
                st[rloc * 4 + 0] = m_s[r]; st[rloc * 4 + 1] = l_s[r];
                st[rloc * 4 + 2] = m_g[r]; st[rloc * 4 + 3] = l_g[r];
            }
        }
    }
}

// ------------------------------------------- combine two K-chunks (qi>=64)
__global__ __launch_bounds__(256) void acomb_kernel(
    const __hip_bfloat16* __restrict__ Opart, const float* __restrict__ stats,
    const float* __restrict__ gate, __hip_bfloat16* __restrict__ comb)
{
    const int qi = 64 + blockIdx.x;          // 64..127
    const int h = blockIdx.y;
    const int tid = threadIdx.x;
    const int rloc = tid >> 4;               // 0..15
    const int c4 = (tid & 15) << 2;          // 4 cols per thread
    const int row = (qi << 4) + rloc;
    const int slot0 = ((h << 6) | (qi - 64)) * 2;
    const float* st0 = stats + slot0 * 64 + rloc * 4;
    const float* st1 = stats + (slot0 + 1) * 64 + rloc * 4;
    float m0 = st0[0], l0 = st0[1], g0 = st0[2], n0 = st0[3];
    float m1 = st1[0], l1 = st1[1], g1 = st1[2], n1 = st1[3];
    float ms = fmaxf(m0, m1);
    float w0 = __expf(m0 - ms), w1 = __expf(m1 - ms);
    float ls = l0 * w0 + l1 * w1;
    float mg = fmaxf(g0, g1);
    float v0 = __expf(g0 - mg), v1 = __expf(g1 - mg);
    float lg = n0 * v0 + n1 * v1;
    const float g = gate[row];
    const float fs = (1.f - g) / ls, fg = g / lg;
    const __hip_bfloat16* o0 = Opart + (size_t)slot0 * 2048 + rloc * 128;
    const __hip_bfloat16* o1 = Opart + (size_t)(slot0 + 1) * 2048 + rloc * 128;
    #pragma unroll
    for (int c = 0; c < 4; ++c) {
        const int col = c4 + c;
        float os = __bfloat162float(o0[col]) * w0 + __bfloat162float(o1[col]) * w1;
        float og = __bfloat162float(o0[64 + col]) * v0 + __bfloat162float(o1[64 + col]) * v1;
        comb[(size_t)row * DD + h * 64 + col] = __float2bfloat16(os * fs + og * fg);
    }
}

// ---------------------------------------------------------------- launch
extern "C" void kernel_launch(void* const* d_in, const int* in_sizes, int n_in,
                              void* d_out, int out_size, void* d_ws, size_t ws_size,
                              hipStream_t stream) {
    (void)in_sizes; (void)n_in; (void)out_size; (void)ws_size;
    const float* x      = (const float*)d_in[0];
    const float* ln1_g  = (const float*)d_in[1];
    const float* ln1_b  = (const float*)d_in[2];
    const float* qkv_w  = (const float*)d_in[3];
    const float* qkv_b  = (const float*)d_in[4];
    const float* w1w    = (const float*)d_in[5];
    const float* w2w    = (const float*)d_in[6];
    const float* w1r    = (const float*)d_in[7];
    const float* w2r    = (const float*)d_in[8];
    const float* gvw    = (const float*)d_in[9];
    const float* gvb    = (const float*)d_in[10];
    const float* gw     = (const float*)d_in[11];
    const float* gb     = (const float*)d_in[12];
    const float* isc    = (const float*)d_in[13];
    const float* ow     = (const float*)d_in[14];
    const float* ob     = (const float*)d_in[15];
    const float* ln2_g  = (const float*)d_in[16];
    const float* ln2_b  = (const float*)d_in[17];
    const float* fcw    = (const float*)d_in[18];
    const float* fcb    = (const float*)d_in[19];
    const float* pw     = (const float*)d_in[20];
    const float* pb     = (const float*)d_in[21];
    float* out = (float*)d_out;
    char* wsb  = (char*)d_ws;

    // workspace layout (bytes), total ~38.6 MB
    __hip_bfloat16* qkvB  = (__hip_bfloat16*)(wsb + 0);          //  9,437,184 bf16 [2048,2304]
    __hip_bfloat16* geovB = (__hip_bfloat16*)(wsb + 9437184);    //  3,145,728 bf16 [2048,768]
    __hip_bfloat16* VTb   = (__hip_bfloat16*)(wsb + 12582912);   //  3,145,728 bf16 [12][64][2048]
    __hip_bfloat16* GVTb  = (__hip_bfloat16*)(wsb + 15728640);   //  3,145,728
    __hip_bfloat16* rlb   = (__hip_bfloat16*)(wsb + 18874368);   //    393,216 bf16 [12][2048][8]
    __hip_bfloat16* jwb   = (__hip_bfloat16*)(wsb + 19267584);   //    393,216
    float*          gate  = (float*)(wsb + 19660800);            //      8,192
    __hip_bfloat16* ln1   = (__hip_bfloat16*)(wsb + 19668992);   //  3,145,728 (reused for ln2)
    __hip_bfloat16* comb  = (__hip_bfloat16*)(wsb + 22814720);   //  3,145,728
    float*          hbuf  = (float*)(wsb + 25960448);            //  6,291,456 fp32 [2048,768]
    __hip_bfloat16* qkvwt = (__hip_bfloat16*)(wsb + 32251904);   //  3,538,944 bf16 [2304,768]
    __hip_bfloat16* gvwt  = (__hip_bfloat16*)(wsb + 35790848);   //  1,179,648 bf16 [768,768]
    __hip_bfloat16* owt   = (__hip_bfloat16*)(wsb + 36970496);   //  1,179,648 bf16 [768,768]
    float*          stats = (float*)(wsb + 38150144);            //    393,216 fp32 [1536][16][4]
    // attention partials reuse hbuf region (hbuf written only after attention):
    __hip_bfloat16* Opart = (__hip_bfloat16*)hbuf;               //  6,291,456 bf16 [1536][16][128]
    // reuse (producers dead by then):
    __hip_bfloat16* fcwt  = qkvwt;                               //  4,718,592 [3072,768]
    __hip_bfloat16* pwt   = (__hip_bfloat16*)(wsb + 0);          //  4,718,592 [768,3072]
    __hip_bfloat16* fcact = (__hip_bfloat16*)(wsb + 4718592);    // 12,582,912 [2048,3072]

    castT_kernel<<<dim3(72, 24), 256, 0, stream>>>(qkv_w, qkvwt, 768, 2304);
    castT_kernel<<<dim3(24, 24), 256, 0, stream>>>(gvw, gvwt, 768, 768);
    ln_kernel<<<TT, 256, 0, stream>>>(x, ln1_g, ln1_b, ln1);
    mgemm_kernel<<<dim3(18, 16), 256, 0, stream>>>(ln1, qkvwt, qkv_b, nullptr, qkvB, TT, 2304, 768, 0, 1);
    mgemm_kernel<<<dim3(6, 16), 256, 0, stream>>>(ln1, gvwt, gvb, nullptr, geovB, TT, 768, 768, 0, 1);
    vt_kernel<<<dim3(32, 12, 2), 256, 0, stream>>>(qkvB, geovB, VTb, GVTb);
    smallproj_kernel<<<TT, 256, 0, stream>>>(ln1, w1w, w2w, w1r, w2r, gw, gb, rlb, jwb, gate);
    mattn_kernel<<<dim3(192, 12), 64, 0, stream>>>(qkvB, VTb, GVTb, rlb, jwb, gate, isc, comb, Opart, stats);
    acomb_kernel<<<dim3(64, 12), 256, 0, stream>>>(Opart, stats, gate, comb);
    castT_kernel<<<dim3(24, 24), 256, 0, stream>>>(ow, owt, 768, 768);
    mgemm_kernel<<<dim3(6, 16), 256, 0, stream>>>(comb, owt, ob, x, hbuf, TT, 768, 768, 2, 0);
    ln_kernel<<<TT, 256, 0, stream>>>(hbuf, ln2_g, ln2_b, ln1);
    castT_kernel<<<dim3(96, 24), 256, 0, stream>>>(fcw, fcwt, 768, 3072);
    mgemm_kernel<<<dim3(24, 16), 256, 0, stream>>>(ln1, fcwt, fcb, nullptr, fcact, TT, 3072, 768, 1, 1);
    castT_kernel<<<dim3(24, 96), 256, 0, stream>>>(pw, pwt, 3072, 768);
    mgemm_kernel<<<dim3(6, 16), 256, 0, stream>>>(fcact, pwt, pb, hbuf, out, TT, 768, 3072, 2, 0);
}

// Round 10
// 479.389 us; speedup vs baseline: 1.0875x; 1.0875x over previous
//
#include <hip/hip_runtime.h>
#include <hip/hip_bf16.h>
#include <math.h>

#define TT 2048
#define DD 768

typedef __bf16 bf16x8 __attribute__((ext_vector_type(8)));
typedef float f32x4 __attribute__((ext_vector_type(4)));

__device__ __forceinline__ void gload16(const void* g, void* l) {
    __builtin_amdgcn_global_load_lds(
        (const __attribute__((address_space(1))) unsigned int*)g,
        (__attribute__((address_space(3))) unsigned int*)l, 16, 0, 0);
}

__device__ __forceinline__ bf16x8 zero8() {
    bf16x8 v;
    #pragma unroll
    for (int j = 0; j < 8; ++j) v[j] = (__bf16)0.0f;
    return v;
}

// ---------------------------------------------------------------- LayerNorm (fp32 in -> bf16 out)
__global__ __launch_bounds__(256) void ln_kernel(const float* __restrict__ in,
    const float* __restrict__ g, const float* __restrict__ b,
    __hip_bfloat16* __restrict__ out)
{
    const int t = blockIdx.x;
    const int tid = threadIdx.x;
    const float* row = in + (size_t)t * DD;
    float x0 = row[tid], x1 = row[tid + 256], x2 = row[tid + 512];
    float s = x0 + x1 + x2;
    float q = x0 * x0 + x1 * x1 + x2 * x2;
    #pragma unroll
    for (int m = 1; m < 64; m <<= 1) {
        s += __shfl_xor(s, m);
        q += __shfl_xor(q, m);
    }
    __shared__ float ssum[4], sqsum[4];
    const int w = tid >> 6;
    if ((tid & 63) == 0) { ssum[w] = s; sqsum[w] = q; }
    __syncthreads();
    s = ssum[0] + ssum[1] + ssum[2] + ssum[3];
    q = sqsum[0] + sqsum[1] + sqsum[2] + sqsum[3];
    const float mean = s * (1.0f / DD);
    const float var = q * (1.0f / DD) - mean * mean;
    const float rs = rsqrtf(var + 1e-5f);
    __hip_bfloat16* orow = out + (size_t)t * DD;
    orow[tid]       = __float2bfloat16((x0 - mean) * rs * g[tid]       + b[tid]);
    orow[tid + 256] = __float2bfloat16((x1 - mean) * rs * g[tid + 256] + b[tid + 256]);
    orow[tid + 512] = __float2bfloat16((x2 - mean) * rs * g[tid + 512] + b[tid + 512]);
}

// ------------------------------------------- transpose + cast: fp32 [K,N] -> bf16 [N,K]
__global__ __launch_bounds__(256) void castT_kernel(const float* __restrict__ in,
    __hip_bfloat16* __restrict__ out, int K, int N)
{
    __shared__ float t[32][33];
    const int n0 = blockIdx.x << 5, k0 = blockIdx.y << 5;
    const int tx = threadIdx.x & 31, ty = threadIdx.x >> 5;
    #pragma unroll
    for (int i = 0; i < 32; i += 8)
        t[ty + i][tx] = in[(size_t)(k0 + ty + i) * N + n0 + tx];
    __syncthreads();
    #pragma unroll
    for (int i = 0; i < 32; i += 8)
        out[(size_t)(n0 + ty + i) * K + k0 + tx] = __float2bfloat16(t[tx][ty + i]);
}

// ---------------------------------------------------------------- MFMA GEMM
// C[M,N] = A[M,K](bf16) @ Bt[N,K]^T(bf16) + bias(fp32)
// epi: 0=none, 1=gelu, 2=+resid(fp32) ; omode: 1=bf16 out, else fp32 out
__device__ __forceinline__ float gelu_f(float x) {
    float u = 0.7978845608028654f * (x + 0.044715f * x * x * x);
    return 0.5f * x * (1.0f + tanhf(u));
}

__global__ __launch_bounds__(256) void mgemm_kernel(
    const __hip_bfloat16* __restrict__ A, const __hip_bfloat16* __restrict__ Bt,
    const float* __restrict__ bias, const float* __restrict__ resid,
    void* __restrict__ Cout, int M, int N, int K, int epi, int omode)
{
    __shared__ __hip_bfloat16 As[128 * 32];
    __shared__ __hip_bfloat16 Bs[128 * 32];
    const int tid = threadIdx.x;
    const int lane = tid & 63, wv = tid >> 6;
    const int wm = wv >> 1, wn = wv & 1;
    const int rowBase = blockIdx.y << 7, colBase = blockIdx.x << 7;

    f32x4 acc[4][4];
    #pragma unroll
    for (int i = 0; i < 4; ++i)
        #pragma unroll
        for (int j = 0; j < 4; ++j) acc[i][j] = (f32x4){0.f, 0.f, 0.f, 0.f};

    const int lr = lane >> 2;
    const int pc = lane & 3;
    const int r0 = wv << 5;
    const int lrow0 = r0 + lr, lrow1 = r0 + 16 + lr;
    const int c0 = (pc ^ ((lrow0 >> 1) & 3)) << 3;
    const int c1 = (pc ^ ((lrow1 >> 1) & 3)) << 3;
    const int m = lane & 15, q = lane >> 4;

    for (int k0 = 0; k0 < K; k0 += 32) {
        __syncthreads();
        gload16(A  + (size_t)(rowBase + lrow0) * K + k0 + c0, &As[(size_t)r0 * 32]);
        gload16(A  + (size_t)(rowBase + lrow1) * K + k0 + c1, &As[(size_t)(r0 + 16) * 32]);
        gload16(Bt + (size_t)(colBase + lrow0) * K + k0 + c0, &Bs[(size_t)r0 * 32]);
        gload16(Bt + (size_t)(colBase + lrow1) * K + k0 + c1, &Bs[(size_t)(r0 + 16) * 32]);
        __syncthreads();

        bf16x8 af[4], bfr[4];
        #pragma unroll
        for (int i = 0; i < 4; ++i) {
            int row = (wm << 6) + (i << 4) + m;
            int pos = q ^ ((row >> 1) & 3);
            af[i] = *(const bf16x8*)&As[row * 32 + (pos << 3)];
        }
        #pragma unroll
        for (int j = 0; j < 4; ++j) {
            int row = (wn << 6) + (j << 4) + m;
            int pos = q ^ ((row >> 1) & 3);
            bfr[j] = *(const bf16x8*)&Bs[row * 32 + (pos << 3)];
        }
        #pragma unroll
        for (int i = 0; i < 4; ++i)
            #pragma unroll
            for (int j = 0; j < 4; ++j)
                acc[i][j] = __builtin_amdgcn_mfma_f32_16x16x32_bf16(af[i], bfr[j], acc[i][j], 0, 0, 0);
    }

    #pragma unroll
    for (int j = 0; j < 4; ++j) {
        const int col = colBase + (wn << 6) + (j << 4) + m;
        const float bj = bias[col];
        #pragma unroll
        for (int i = 0; i < 4; ++i) {
            #pragma unroll
            for (int r = 0; r < 4; ++r) {
                const int row = rowBase + (wm << 6) + (i << 4) + (q << 2) + r;
                float v = acc[i][j][r] + bj;
                if (epi == 1) v = gelu_f(v);
                else if (epi == 2) v += resid[(size_t)row * N + col];
                if (omode == 1) ((__hip_bfloat16*)Cout)[(size_t)row * N + col] = __float2bfloat16(v);
                else ((float*)Cout)[(size_t)row * N + col] = v;
            }
        }
    }
}

// ------------------------------------------------- small projections + exterior
__device__ __forceinline__ void exterior6(const float* a, const float* b, float* L) {
    L[0] = a[0] * b[1] - a[1] * b[0];
    L[1] = a[0] * b[2] - a[2] * b[0];
    L[2] = a[0] * b[3] - a[3] * b[0];
    L[3] = a[1] * b[2] - a[2] * b[1];
    L[4] = a[1] * b[3] - a[3] * b[1];
    L[5] = a[2] * b[3] - a[3] * b[2];
    float n = sqrtf(L[0]*L[0] + L[1]*L[1] + L[2]*L[2] + L[3]*L[3] + L[4]*L[4] + L[5]*L[5]);
    float inv = 1.f / fmaxf(n, 1e-12f);
    #pragma unroll
    for (int p = 0; p < 6; ++p) L[p] *= inv;
}

// outputs: rlb/jwb bf16 [12][2048][8] (6 real + 2 zero pad), gate fp32 [2048]
__global__ __launch_bounds__(256) void smallproj_kernel(
    const __hip_bfloat16* __restrict__ ln1,
    const float* __restrict__ w1w, const float* __restrict__ w2w,
    const float* __restrict__ w1r, const float* __restrict__ w2r,
    const float* __restrict__ gw, const float* __restrict__ gb,
    __hip_bfloat16* __restrict__ rlb, __hip_bfloat16* __restrict__ jwb,
    float* __restrict__ gate)
{
    const int t = blockIdx.x;
    const int tid = threadIdx.x;
    __shared__ float xc[768], xp[768], res[204];
    const __hip_bfloat16* cur = ln1 + (size_t)t * DD;
    #pragma unroll
    for (int i = 0; i < 3; ++i) {
        int idx = tid + (i << 8);
        xc[idx] = __bfloat162float(cur[idx]);
        xp[idx] = (t > 0) ? __bfloat162float(cur[idx - DD]) : 0.f;
    }
    __syncthreads();
    if (tid < 204) {
        const float* wsel; const float* xv; int col, stride;
        if (tid < 48)       { wsel = w2w; xv = xc; col = tid;       stride = 48; }
        else if (tid < 96)  { wsel = w1w; xv = xp; col = tid - 48;  stride = 48; }
        else if (tid < 144) { wsel = w1r; xv = xc; col = tid - 96;  stride = 48; }
        else if (tid < 192) { wsel = w2r; xv = xc; col = tid - 144; stride = 48; }
        else                { wsel = gw;  xv = xc; col = tid - 192; stride = 12; }
        float s = 0.f;
        for (int k = 0; k < 768; ++k) s += xv[k] * wsel[(size_t)k * stride + col];
        if (tid >= 192) s += gb[col];
        res[tid] = s;
    }
    __syncthreads();
    if (tid < 12) {
        const int h = tid;
        float a[4], b[4], L[6];
        // write lines: exterior(w1(x_prev), w2(x)) then J6 = [L5,-L4,L3,L2,-L1,L0]
        #pragma unroll
        for (int i = 0; i < 4; ++i) { a[i] = res[48 + h * 4 + i]; b[i] = res[h * 4 + i]; }
        exterior6(a, b, L);
        __hip_bfloat16* jwp = jwb + (size_t)h * 16384 + t * 8;
        jwp[0] = __float2bfloat16( L[5]); jwp[1] = __float2bfloat16(-L[4]);
        jwp[2] = __float2bfloat16( L[3]); jwp[3] = __float2bfloat16( L[2]);
        jwp[4] = __float2bfloat16(-L[1]); jwp[5] = __float2bfloat16( L[0]);
        jwp[6] = __float2bfloat16(0.f);   jwp[7] = __float2bfloat16(0.f);
        // read lines: exterior(r1, r2)
        #pragma unroll
        for (int i = 0; i < 4; ++i) { a[i] = res[96 + h * 4 + i]; b[i] = res[144 + h * 4 + i]; }
        exterior6(a, b, L);
        __hip_bfloat16* rlp = rlb + (size_t)h * 16384 + t * 8;
        #pragma unroll
        for (int p = 0; p < 6; ++p) rlp[p] = __float2bfloat16(L[p]);
        rlp[6] = __float2bfloat16(0.f); rlp[7] = __float2bfloat16(0.f);
    }
    if (tid == 0) {
        float g = 0.f;
        #pragma unroll
        for (int i = 0; i < 12; ++i) g += 1.f / (1.f + __expf(-res[192 + i]));
        gate[t] = g * (1.f / 12.f);
    }
}

// ------------------------------------------- per-head transpose: V/GV -> VT[h][64][2048]
__global__ __launch_bounds__(256) void vt_kernel(
    const __hip_bfloat16* __restrict__ qkvB, const __hip_bfloat16* __restrict__ geovB,
    __hip_bfloat16* __restrict__ VT, __hip_bfloat16* __restrict__ GVT)
{
    __shared__ __hip_bfloat16 tile[64][72];
    const int s0 = blockIdx.x << 6, h = blockIdx.y;
    const bool isGV = (blockIdx.z != 0);
    const __hip_bfloat16* src = isGV ? (geovB + h * 64) : (qkvB + 1536 + h * 64);
    const int stride = isGV ? 768 : 2304;
    __hip_bfloat16* dst = (isGV ? GVT : VT) + (size_t)h * 131072;
    const int tid = threadIdx.x;
    const int r = tid >> 2, c = (tid & 3) << 3;
    *(bf16x8*)&tile[r][c]      = *(const bf16x8*)&src[(size_t)(s0 + r) * stride + c];
    *(bf16x8*)&tile[r][c + 32] = *(const bf16x8*)&src[(size_t)(s0 + r) * stride + c + 32];
    __syncthreads();
    __hip_bfloat16 tmp[8];
    #pragma unroll
    for (int j = 0; j < 8; ++j) tmp[j] = tile[c + j][r];
    *(bf16x8*)&dst[(size_t)r * 2048 + s0 + c] = *(const bf16x8*)tmp;
    #pragma unroll
    for (int j = 0; j < 8; ++j) tmp[j] = tile[c + 32 + j][r];
    *(bf16x8*)&dst[(size_t)r * 2048 + s0 + c + 32] = *(const bf16x8*)tmp;
}

// ---------------------------------------------------------------- MFMA dual-path flash attention
// Balanced K-split: job j (per head) -> (qt, chunk c of nc) with
// nc = 1 (qt<12) / 2 (qt<24) / 3 (qt>=24); chunk covers k-tiles
// [c*nk/nc, (c+1)*nk/nc). 4 waves, 64-row q tile, LDS-staged tiles,
// register prefetch. nc==1 writes comb; else unnormalized partials + stats.
__global__ __launch_bounds__(256) void mattn_kernel(
    const __hip_bfloat16* __restrict__ qkvB, const __hip_bfloat16* __restrict__ VT,
    const __hip_bfloat16* __restrict__ GVT, const __hip_bfloat16* __restrict__ rlb,
    const __hip_bfloat16* __restrict__ jwb, const float* __restrict__ gate,
    const float* __restrict__ inc_scale, __hip_bfloat16* __restrict__ comb,
    __hip_bfloat16* __restrict__ Opart, float* __restrict__ stats)
{
    __shared__ __hip_bfloat16 Ks[64][72];    // [s][d]
    __shared__ __hip_bfloat16 VTs[64][72];   // [d][s]
    __shared__ __hip_bfloat16 GVTs[64][72];  // [d][s]
    __shared__ __hip_bfloat16 JWs[64][8];    // [s][p(6+2pad)]
    __shared__ __bf16 Ps[64][72];            // P std [q][s]
    __shared__ __bf16 Pg[64][72];            // P geo

    const int j = 59 - blockIdx.x;           // longest jobs dispatch first
    const int h = blockIdx.z ? 0 : blockIdx.y;   // (grid.z unused; keep y=head)
    (void)h;
    const int hh = blockIdx.y;
    int qt, c, nc;
    if (j < 12)      { qt = j; c = 0; nc = 1; }
    else if (j < 36) { int t2 = j - 12; qt = 12 + (t2 >> 1); c = t2 & 1; nc = 2; }
    else             { int t2 = j - 36; int d3 = t2 / 3; qt = 24 + d3; c = t2 - d3 * 3; nc = 3; }
    const int q0 = qt << 6;
    const int nk = qt + 1;
    const int ktb = c * nk / nc;
    const int kte = (c + 1) * nk / nc - 1;
    const int tid = threadIdx.x;
    const int w = tid >> 6, lane = tid & 63;
    const int n = lane & 15, quad = lane >> 4;

    // Q fragments (A-layout: lane m=n holds row q0+16w+n, k=quad*8+jj)
    const int qrow = q0 + (w << 4) + n;
    const size_t qb = (size_t)qrow * 2304 + hh * 64;
    bf16x8 af0 = *(const bf16x8*)&qkvB[qb + (quad << 3)];
    bf16x8 af1 = *(const bf16x8*)&qkvB[qb + 32 + (quad << 3)];
    bf16x8 rlA = zero8();
    if (quad == 0) rlA = *(const bf16x8*)&rlb[(size_t)hh * 16384 + (size_t)qrow * 8];
    const float isc = inc_scale[hh];
    const size_t vbase = (size_t)hh * 131072;

    const int sRow = tid >> 2, sChk = (tid & 3) << 3;   // cols sChk, sChk+32

    f32x4 Os[4], Og[4];
    float m_s[4], l_s[4], m_g[4], l_g[4];
    #pragma unroll
    for (int r = 0; r < 4; ++r) {
        m_s[r] = -1e30f; l_s[r] = 0.f; m_g[r] = -1e30f; l_g[r] = 0.f;
        Os[r] = (f32x4){0.f, 0.f, 0.f, 0.f};
        Og[r] = (f32x4){0.f, 0.f, 0.f, 0.f};
    }

    // prefetch first tile into registers
    bf16x8 rK0, rK1, rV0, rV1, rG0, rG1, rJ = zero8();
    {
        const int k0 = ktb << 6;
        const size_t kb = (size_t)(k0 + sRow) * 2304 + 768 + hh * 64;
        const size_t vb = vbase + (size_t)sRow * 2048 + k0;
        rK0 = *(const bf16x8*)&qkvB[kb + sChk];
        rK1 = *(const bf16x8*)&qkvB[kb + sChk + 32];
        rV0 = *(const bf16x8*)&VT[vb + sChk];
        rV1 = *(const bf16x8*)&VT[vb + sChk + 32];
        rG0 = *(const bf16x8*)&GVT[vb + sChk];
        rG1 = *(const bf16x8*)&GVT[vb + sChk + 32];
        if (tid < 64) rJ = *(const bf16x8*)&jwb[(size_t)hh * 16384 + (size_t)(k0 + tid) * 8];
    }

    for (int kt = ktb; kt <= kte; ++kt) {
        const int k0 = kt << 6;
        __syncthreads();   // prior reads of LDS tiles done
        *(bf16x8*)&Ks[sRow][sChk]        = rK0;
        *(bf16x8*)&Ks[sRow][sChk + 32]   = rK1;
        *(bf16x8*)&VTs[sRow][sChk]       = rV0;
        *(bf16x8*)&VTs[sRow][sChk + 32]  = rV1;
        *(bf16x8*)&GVTs[sRow][sChk]      = rG0;
        *(bf16x8*)&GVTs[sRow][sChk + 32] = rG1;
        if (tid < 64) *(bf16x8*)&JWs[tid][0] = rJ;
        if (kt < kte) {
            const int k1 = (kt + 1) << 6;
            const size_t kb = (size_t)(k1 + sRow) * 2304 + 768 + hh * 64;
            const size_t vb = vbase + (size_t)sRow * 2048 + k1;
            rK0 = *(const bf16x8*)&qkvB[kb + sChk];
            rK1 = *(const bf16x8*)&qkvB[kb + sChk + 32];
            rV0 = *(const bf16x8*)&VT[vb + sChk];
            rV1 = *(const bf16x8*)&VT[vb + sChk + 32];
            rG0 = *(const bf16x8*)&GVT[vb + sChk];
            rG1 = *(const bf16x8*)&GVT[vb + sChk + 32];
            if (tid < 64) rJ = *(const bf16x8*)&jwb[(size_t)hh * 16384 + (size_t)(k1 + tid) * 8];
        }
        __syncthreads();   // LDS tiles ready

        // ---- S = QK^T (std) and RL·JW (geo), 4 col-tiles of 16
        f32x4 Ss[4], Sg[4];
        #pragma unroll
        for (int t = 0; t < 4; ++t) {
            Ss[t] = (f32x4){0.f, 0.f, 0.f, 0.f};
            Sg[t] = (f32x4){0.f, 0.f, 0.f, 0.f};
        }
        #pragma unroll
        for (int t = 0; t < 4; ++t) {
            bf16x8 kb0 = *(const bf16x8*)&Ks[(t << 4) + n][(quad << 3)];
            bf16x8 kb1 = *(const bf16x8*)&Ks[(t << 4) + n][32 + (quad << 3)];
            Ss[t] = __builtin_amdgcn_mfma_f32_16x16x32_bf16(af0, kb0, Ss[t], 0, 0, 0);
            Ss[t] = __builtin_amdgcn_mfma_f32_16x16x32_bf16(af1, kb1, Ss[t], 0, 0, 0);
            bf16x8 jb = zero8();
            if (quad == 0) jb = *(const bf16x8*)&JWs[(t << 4) + n][0];
            Sg[t] = __builtin_amdgcn_mfma_f32_16x16x32_bf16(rlA, jb, Sg[t], 0, 0, 0);
        }
        // scale + causal mask (diagonal k-tile only; lives in the last chunk)
        #pragma unroll
        for (int t = 0; t < 4; ++t) {
            #pragma unroll
            for (int r = 0; r < 4; ++r) { Ss[t][r] *= 0.125f; Sg[t][r] *= isc; }
        }
        if (kt == qt) {
            #pragma unroll
            for (int t = 0; t < 4; ++t) {
                const int sg = k0 + (t << 4) + n;
                #pragma unroll
                for (int r = 0; r < 4; ++r) {
                    const int qg = q0 + (w << 4) + (quad << 2) + r;
                    if (sg > qg) { Ss[t][r] = -1e30f; Sg[t][r] = -1e30f; }
                }
            }
        }

        // ---- online softmax, both paths; Ss/Sg -> probabilities
        #pragma unroll
        for (int r = 0; r < 4; ++r) {
            float mx = fmaxf(fmaxf(Ss[0][r], Ss[1][r]), fmaxf(Ss[2][r], Ss[3][r]));
            #pragma unroll
            for (int mk = 1; mk < 16; mk <<= 1) mx = fmaxf(mx, __shfl_xor(mx, mk));
            float mnew = fmaxf(m_s[r], mx);
            float alpha = __expf(m_s[r] - mnew);
            m_s[r] = mnew;
            float sm = 0.f;
            #pragma unroll
            for (int t = 0; t < 4; ++t) { Ss[t][r] = __expf(Ss[t][r] - mnew); sm += Ss[t][r]; }
            #pragma unroll
            for (int mk = 1; mk < 16; mk <<= 1) sm += __shfl_xor(sm, mk);
            l_s[r] = l_s[r] * alpha + sm;
            #pragma unroll
            for (int t = 0; t < 4; ++t) Os[t][r] *= alpha;

            float mxg = fmaxf(fmaxf(Sg[0][r], Sg[1][r]), fmaxf(Sg[2][r], Sg[3][r]));
            #pragma unroll
            for (int mk = 1; mk < 16; mk <<= 1) mxg = fmaxf(mxg, __shfl_xor(mxg, mk));
            float mnewg = fmaxf(m_g[r], mxg);
            float alphag = __expf(m_g[r] - mnewg);
            m_g[r] = mnewg;
            float smg = 0.f;
            #pragma unroll
            for (int t = 0; t < 4; ++t) { Sg[t][r] = __expf(Sg[t][r] - mnewg); smg += Sg[t][r]; }
            #pragma unroll
            for (int mk = 1; mk < 16; mk <<= 1) smg += __shfl_xor(smg, mk);
            l_g[r] = l_g[r] * alphag + smg;
            #pragma unroll
            for (int t = 0; t < 4; ++t) Og[t][r] *= alphag;
        }

        // ---- P -> LDS (C-layout), fence, then PV A-fragment reads
        #pragma unroll
        for (int t = 0; t < 4; ++t) {
            #pragma unroll
            for (int r = 0; r < 4; ++r) {
                Ps[(w << 4) + (quad << 2) + r][(t << 4) + n] = (__bf16)Ss[t][r];
                Pg[(w << 4) + (quad << 2) + r][(t << 4) + n] = (__bf16)Sg[t][r];
            }
        }
        __syncthreads();   // P stores visible before PV fragment loads

        // ---- PV for both paths: Os[dt] += P · V, Og[dt] += Pg · GV
        #pragma unroll
        for (int st = 0; st < 2; ++st) {
            bf16x8 ap = *(const bf16x8*)&Ps[(w << 4) + n][(st << 5) + (quad << 3)];
            bf16x8 gp = *(const bf16x8*)&Pg[(w << 4) + n][(st << 5) + (quad << 3)];
            #pragma unroll
            for (int dt = 0; dt < 4; ++dt) {
                bf16x8 vb2 = *(const bf16x8*)&VTs[(dt << 4) + n][(st << 5) + (quad << 3)];
                bf16x8 gb2 = *(const bf16x8*)&GVTs[(dt << 4) + n][(st << 5) + (quad << 3)];
                Os[dt] = __builtin_amdgcn_mfma_f32_16x16x32_bf16(ap, vb2, Os[dt], 0, 0, 0);
                Og[dt] = __builtin_amdgcn_mfma_f32_16x16x32_bf16(gp, gb2, Og[dt], 0, 0, 0);
            }
        }
    }

    if (nc == 1) {
        // ---- direct epilogue: combine with gate, write bf16
        #pragma unroll
        for (int r = 0; r < 4; ++r) {
            const int row = q0 + (w << 4) + (quad << 2) + r;
            const float g = gate[row];
            const float invs = (1.f - g) / l_s[r], invg = g / l_g[r];
            #pragma unroll
            for (int dt = 0; dt < 4; ++dt) {
                float val = Os[dt][r] * invs + Og[dt][r] * invg;
                comb[(size_t)row * DD + hh * 64 + (dt << 4) + n] = __float2bfloat16(val);
            }
        }
    } else {
        // ---- partial epilogue: unnormalized O (bf16) + per-row stats
        const int base = (qt < 24) ? ((qt - 12) << 1) : (24 + (qt - 24) * 3);
        const int slot = hh * 48 + base + c;
        __hip_bfloat16* op = Opart + (size_t)slot * 8192;    // [row64][path2*col64]
        float* st = stats + (size_t)slot * 256;               // [row64][4]
        #pragma unroll
        for (int r = 0; r < 4; ++r) {
            const int rloc = (w << 4) + (quad << 2) + r;
            #pragma unroll
            for (int dt = 0; dt < 4; ++dt) {
                const int col = (dt << 4) + n;
                op[rloc * 128 + col]      = __float2bfloat16(Os[dt][r]);
                op[rloc * 128 + 64 + col] = __float2bfloat16(Og[dt][r]);
            }
            if (n == 0) {
                st[rloc * 4 + 0] = m_s[r]; st[rloc * 4 + 1] = l_s[r];
                st[rloc * 4 + 2] = m_g[r]; st[rloc * 4 + 3] = l_g[r];
            }
        }
    }
}

// ------------------------------------------- combine 2-3 K-chunks (qt>=12)
__global__ __launch_bounds__(256) void acomb_kernel(
    const __hip_bfloat16* __restrict__ Opart, const float* __restrict__ stats,
    const float* __restrict__ gate, __hip_bfloat16* __restrict__ comb)
{
    const int qt = 12 + blockIdx.x;          // 12..31
    const int h = blockIdx.y;
    const int nc = (qt < 24) ? 2 : 3;
    const int sb = h * 48 + ((qt < 24) ? ((qt - 12) << 1) : (24 + (qt - 24) * 3));
    const int tid = threadIdx.x;
    const int rloc = tid >> 2;               // 0..63
    const int cseg = (tid & 3) << 4;         // 16 cols per thread
    const int row = (qt << 6) + rloc;
    float ms = -1e30f, mg = -1e30f;
    for (int c = 0; c < nc; ++c) {
        const float* st = stats + (size_t)(sb + c) * 256 + rloc * 4;
        ms = fmaxf(ms, st[0]);
        mg = fmaxf(mg, st[2]);
    }
    float wsc[3], wgc[3];
    float ls = 0.f, lg = 0.f;
    for (int c = 0; c < nc; ++c) {
        const float* st = stats + (size_t)(sb + c) * 256 + rloc * 4;
        wsc[c] = __expf(st[0] - ms); ls += st[1] * wsc[c];
        wgc[c] = __expf(st[2] - mg); lg += st[3] * wgc[c];
    }
    const float g = gate[row];
    const float fs = (1.f - g) / ls, fg = g / lg;
    #pragma unroll
    for (int cc = 0; cc < 16; ++cc) {
        const int col = cseg + cc;
        float os = 0.f, og = 0.f;
        for (int c = 0; c < nc; ++c) {
            const __hip_bfloat16* op = Opart + (size_t)(sb + c) * 8192 + rloc * 128;
            os += __bfloat162float(op[col]) * wsc[c];
            og += __bfloat162float(op[64 + col]) * wgc[c];
        }
        comb[(size_t)row * DD + h * 64 + col] = __float2bfloat16(os * fs + og * fg);
    }
}

// ---------------------------------------------------------------- launch
extern "C" void kernel_launch(void* const* d_in, const int* in_sizes, int n_in,
                              void* d_out, int out_size, void* d_ws, size_t ws_size,
                              hipStream_t stream) {
    (void)in_sizes; (void)n_in; (void)out_size; (void)ws_size;
    const float* x      = (const float*)d_in[0];
    const float* ln1_g  = (const float*)d_in[1];
    const float* ln1_b  = (const float*)d_in[2];
    const float* qkv_w  = (const float*)d_in[3];
    const float* qkv_b  = (const float*)d_in[4];
    const float* w1w    = (const float*)d_in[5];
    const float* w2w    = (const float*)d_in[6];
    const float* w1r    = (const float*)d_in[7];
    const float* w2r    = (const float*)d_in[8];
    const float* gvw    = (const float*)d_in[9];
    const float* gvb    = (const float*)d_in[10];
    const float* gw     = (const float*)d_in[11];
    const float* gb     = (const float*)d_in[12];
    const float* isc    = (const float*)d_in[13];
    const float* ow     = (const float*)d_in[14];
    const float* ob     = (const float*)d_in[15];
    const float* ln2_g  = (const float*)d_in[16];
    const float* ln2_b  = (const float*)d_in[17];
    const float* fcw    = (const float*)d_in[18];
    const float* fcb    = (const float*)d_in[19];
    const float* pw     = (const float*)d_in[20];
    const float* pb     = (const float*)d_in[21];
    float* out = (float*)d_out;
    char* wsb  = (char*)d_ws;

    // workspace layout (bytes), total ~38.7 MB
    __hip_bfloat16* qkvB  = (__hip_bfloat16*)(wsb + 0);          //  9,437,184 bf16 [2048,2304]
    __hip_bfloat16* geovB = (__hip_bfloat16*)(wsb + 9437184);    //  3,145,728 bf16 [2048,768]
    __hip_bfloat16* VTb   = (__hip_bfloat16*)(wsb + 12582912);   //  3,145,728 bf16 [12][64][2048]
    __hip_bfloat16* GVTb  = (__hip_bfloat16*)(wsb + 15728640);   //  3,145,728
    __hip_bfloat16* rlb   = (__hip_bfloat16*)(wsb + 18874368);   //    393,216 bf16 [12][2048][8]
    __hip_bfloat16* jwb   = (__hip_bfloat16*)(wsb + 19267584);   //    393,216
    float*          gate  = (float*)(wsb + 19660800);            //      8,192
    __hip_bfloat16* ln1   = (__hip_bfloat16*)(wsb + 19668992);   //  3,145,728 (reused for ln2)
    __hip_bfloat16* comb  = (__hip_bfloat16*)(wsb + 22814720);   //  3,145,728
    float*          hbuf  = (float*)(wsb + 25960448);            //  6,291,456 fp32 [2048,768]
    __hip_bfloat16* qkvwt = (__hip_bfloat16*)(wsb + 32251904);   //  3,538,944 bf16 [2304,768]
    __hip_bfloat16* gvwt  = (__hip_bfloat16*)(wsb + 35790848);   //  1,179,648 bf16 [768,768]
    __hip_bfloat16* owt   = (__hip_bfloat16*)(wsb + 36970496);   //  1,179,648 bf16 [768,768]
    float*          stats = (float*)(wsb + 38150144);            //    589,824 fp32 [576][64][4]
    // attention partials: 576 slots x 16KB = 9,437,184 B, overlaying hbuf +
    // qkvwt regions (both dead during mattn/acomb; rewritten after):
    __hip_bfloat16* Opart = (__hip_bfloat16*)hbuf;
    // reuse (producers dead by then):
    __hip_bfloat16* fcwt  = qkvwt;                               //  4,718,592 [3072,768]
    __hip_bfloat16* pwt   = (__hip_bfloat16*)(wsb + 0);          //  4,718,592 [768,3072]
    __hip_bfloat16* fcact = (__hip_bfloat16*)(wsb + 4718592);    // 12,582,912 [2048,3072]

    castT_kernel<<<dim3(72, 24), 256, 0, stream>>>(qkv_w, qkvwt, 768, 2304);
    castT_kernel<<<dim3(24, 24), 256, 0, stream>>>(gvw, gvwt, 768, 768);
    ln_kernel<<<TT, 256, 0, stream>>>(x, ln1_g, ln1_b, ln1);
    mgemm_kernel<<<dim3(18, 16), 256, 0, stream>>>(ln1, qkvwt, qkv_b, nullptr, qkvB, TT, 2304, 768, 0, 1);
    mgemm_kernel<<<dim3(6, 16), 256, 0, stream>>>(ln1, gvwt, gvb, nullptr, geovB, TT, 768, 768, 0, 1);
    vt_kernel<<<dim3(32, 12, 2), 256, 0, stream>>>(qkvB, geovB, VTb, GVTb);
    smallproj_kernel<<<TT, 256, 0, stream>>>(ln1, w1w, w2w, w1r, w2r, gw, gb, rlb, jwb, gate);
    mattn_kernel<<<dim3(60, 12), 256, 0, stream>>>(qkvB, VTb, GVTb, rlb, jwb, gate, isc, comb, Opart, stats);
    acomb_kernel<<<dim3(20, 12), 256, 0, stream>>>(Opart, stats, gate, comb);
    castT_kernel<<<dim3(24, 24), 256, 0, stream>>>(ow, owt, 768, 768);
    mgemm_kernel<<<dim3(6, 16), 256, 0, stream>>>(comb, owt, ob, x, hbuf, TT, 768, 768, 2, 0);
    ln_kernel<<<TT, 256, 0, stream>>>(hbuf, ln2_g, ln2_b, ln1);
    castT_kernel<<<dim3(96, 24), 256, 0, stream>>>(fcw, fcwt, 768, 3072);
    mgemm_kernel<<<dim3(24, 16), 256, 0, stream>>>(ln1, fcwt, fcb, nullptr, fcact, TT, 3072, 768, 1, 1);
    castT_kernel<<<dim3(24, 96), 256, 0, stream>>>(pw, pwt, 3072, 768);
    mgemm_kernel<<<dim3(6, 16), 256, 0, stream>>>(fcact, pwt, pb, hbuf, out, TT, 768, 3072, 2, 0);
}

// Round 11
// 412.388 us; speedup vs baseline: 1.2642x; 1.1625x over previous
//
#include <hip/hip_runtime.h>
#include <hip/hip_bf16.h>
#include <math.h>

#define TT 2048
#define DD 768

typedef __bf16 bf16x8 __attribute__((ext_vector_type(8)));
typedef float f32x4 __attribute__((ext_vector_type(4)));

__device__ __forceinline__ void gload16(const void* g, void* l) {
    __builtin_amdgcn_global_load_lds(
        (const __attribute__((address_space(1))) unsigned int*)g,
        (__attribute__((address_space(3))) unsigned int*)l, 16, 0, 0);
}

__device__ __forceinline__ bf16x8 zero8() {
    bf16x8 v;
    #pragma unroll
    for (int j = 0; j < 8; ++j) v[j] = (__bf16)0.0f;
    return v;
}

// ---------------------------------------------------------------- LayerNorm (fp32 in -> bf16 out)
__global__ __launch_bounds__(256) void ln_kernel(const float* __restrict__ in,
    const float* __restrict__ g, const float* __restrict__ b,
    __hip_bfloat16* __restrict__ out)
{
    const int t = blockIdx.x;
    const int tid = threadIdx.x;
    const float* row = in + (size_t)t * DD;
    float x0 = row[tid], x1 = row[tid + 256], x2 = row[tid + 512];
    float s = x0 + x1 + x2;
    float q = x0 * x0 + x1 * x1 + x2 * x2;
    #pragma unroll
    for (int m = 1; m < 64; m <<= 1) {
        s += __shfl_xor(s, m);
        q += __shfl_xor(q, m);
    }
    __shared__ float ssum[4], sqsum[4];
    const int w = tid >> 6;
    if ((tid & 63) == 0) { ssum[w] = s; sqsum[w] = q; }
    __syncthreads();
    s = ssum[0] + ssum[1] + ssum[2] + ssum[3];
    q = sqsum[0] + sqsum[1] + sqsum[2] + sqsum[3];
    const float mean = s * (1.0f / DD);
    const float var = q * (1.0f / DD) - mean * mean;
    const float rs = rsqrtf(var + 1e-5f);
    __hip_bfloat16* orow = out + (size_t)t * DD;
    orow[tid]       = __float2bfloat16((x0 - mean) * rs * g[tid]       + b[tid]);
    orow[tid + 256] = __float2bfloat16((x1 - mean) * rs * g[tid + 256] + b[tid + 256]);
    orow[tid + 512] = __float2bfloat16((x2 - mean) * rs * g[tid + 512] + b[tid + 512]);
}

// ------------------------------------------- transpose + cast: fp32 [K,N] -> bf16 [N,K]
__global__ __launch_bounds__(256) void castT_kernel(const float* __restrict__ in,
    __hip_bfloat16* __restrict__ out, int K, int N)
{
    __shared__ float t[32][33];
    const int n0 = blockIdx.x << 5, k0 = blockIdx.y << 5;
    const int tx = threadIdx.x & 31, ty = threadIdx.x >> 5;
    #pragma unroll
    for (int i = 0; i < 32; i += 8)
        t[ty + i][tx] = in[(size_t)(k0 + ty + i) * N + n0 + tx];
    __syncthreads();
    #pragma unroll
    for (int i = 0; i < 32; i += 8)
        out[(size_t)(n0 + ty + i) * K + k0 + tx] = __float2bfloat16(t[tx][ty + i]);
}

// ---------------------------------------------------------------- MFMA GEMM (64x128 tile)
// C[M,N] = A[M,K](bf16) @ Bt[N,K]^T(bf16) + bias(fp32)
// kz>1: block z covers K-chunk z; writes fp32 partial (no bias) to Pb0/Pb1.
// epi: 0=none, 1=gelu, 2=+resid(fp32) ; omode: 1=bf16 out, else fp32 out
__device__ __forceinline__ float gelu_f(float x) {
    float u = 0.7978845608028654f * (x + 0.044715f * x * x * x);
    return 0.5f * x * (1.0f + tanhf(u));
}

__global__ __launch_bounds__(256) void mgemm64_kernel(
    const __hip_bfloat16* __restrict__ A, const __hip_bfloat16* __restrict__ Bt,
    const float* __restrict__ bias, const float* __restrict__ resid,
    void* __restrict__ Cout, float* __restrict__ Pb0, float* __restrict__ Pb1,
    int M, int N, int K, int kz, int epi, int omode)
{
    __shared__ __hip_bfloat16 As[64 * 32];
    __shared__ __hip_bfloat16 Bs[128 * 32];
    const int tid = threadIdx.x;
    const int lane = tid & 63, w = tid >> 6;
    const int colBase = blockIdx.x << 7, rowBase = blockIdx.y << 6;
    const int z = blockIdx.z;
    const int Kc = K / kz, koff = z * Kc;

    const int lr = lane >> 2, pc = lane & 3;
    const int n = lane & 15, quad = lane >> 4;

    // staging geometry (XOR swizzle like the proven 128-tile kernel)
    const int arow = (w << 4) + lr;                       // A rows [16w,16w+16)
    const int ac = (pc ^ ((arow >> 1) & 3)) << 3;
    const int brow0 = (w << 5) + lr, brow1 = brow0 + 16;  // B rows [32w,32w+32)
    const int bc0 = (pc ^ ((brow0 >> 1) & 3)) << 3;
    const int bc1 = (pc ^ ((brow1 >> 1) & 3)) << 3;

    f32x4 acc[8];
    #pragma unroll
    for (int j = 0; j < 8; ++j) acc[j] = (f32x4){0.f, 0.f, 0.f, 0.f};

    const int arF = (w << 4) + n;
    const int aposF = (quad ^ ((arF >> 1) & 3)) << 3;

    for (int kk = koff; kk < koff + Kc; kk += 32) {
        __syncthreads();
        gload16(A  + (size_t)(rowBase + arow) * K + kk + ac,   &As[(w << 4) * 32]);
        gload16(Bt + (size_t)(colBase + brow0) * K + kk + bc0, &Bs[(w << 5) * 32]);
        gload16(Bt + (size_t)(colBase + brow1) * K + kk + bc1, &Bs[((w << 5) + 16) * 32]);
        __syncthreads();

        bf16x8 af = *(const bf16x8*)&As[arF * 32 + aposF];
        #pragma unroll
        for (int j = 0; j < 8; ++j) {
            const int rb = (j << 4) + n;
            bf16x8 bfj = *(const bf16x8*)&Bs[rb * 32 + ((quad ^ ((rb >> 1) & 3)) << 3)];
            acc[j] = __builtin_amdgcn_mfma_f32_16x16x32_bf16(af, bfj, acc[j], 0, 0, 0);
        }
    }

    if (kz == 1) {
        #pragma unroll
        for (int j = 0; j < 8; ++j) {
            const int col = colBase + (j << 4) + n;
            const float bj = bias[col];
            #pragma unroll
            for (int r = 0; r < 4; ++r) {
                const int row = rowBase + (w << 4) + (quad << 2) + r;
                float v = acc[j][r] + bj;
                if (epi == 1) v = gelu_f(v);
                else if (epi == 2) v += resid[(size_t)row * N + col];
                if (omode == 1) ((__hip_bfloat16*)Cout)[(size_t)row * N + col] = __float2bfloat16(v);
                else ((float*)Cout)[(size_t)row * N + col] = v;
            }
        }
    } else {
        float* P = (z == 0) ? Pb0 : Pb1;
        #pragma unroll
        for (int j = 0; j < 8; ++j) {
            const int col = colBase + (j << 4) + n;
            #pragma unroll
            for (int r = 0; r < 4; ++r) {
                const int row = rowBase + (w << 4) + (quad << 2) + r;
                P[(size_t)row * N + col] = acc[j][r];
            }
        }
    }
}

// ------------------------------------------- split-K reduce: out = p0+p1+bias+resid (fp32)
__global__ __launch_bounds__(256) void kred_kernel(
    const float* __restrict__ p0, const float* __restrict__ p1,
    const float* __restrict__ bias, const float* __restrict__ resid,
    float* __restrict__ out, int N)
{
    const int base = (blockIdx.x * 256 + threadIdx.x) << 2;
    float4 a = *(const float4*)&p0[base];
    float4 b = *(const float4*)&p1[base];
    float4 bi = *(const float4*)&bias[base % N];
    float4 rs = *(const float4*)&resid[base];
    float4 o;
    o.x = a.x + b.x + bi.x + rs.x;
    o.y = a.y + b.y + bi.y + rs.y;
    o.z = a.z + b.z + bi.z + rs.z;
    o.w = a.w + b.w + bi.w + rs.w;
    *(float4*)&out[base] = o;
}

// ------------------------------------------------- small projections + exterior
__device__ __forceinline__ void exterior6(const float* a, const float* b, float* L) {
    L[0] = a[0] * b[1] - a[1] * b[0];
    L[1] = a[0] * b[2] - a[2] * b[0];
    L[2] = a[0] * b[3] - a[3] * b[0];
    L[3] = a[1] * b[2] - a[2] * b[1];
    L[4] = a[1] * b[3] - a[3] * b[1];
    L[5] = a[2] * b[3] - a[3] * b[2];
    float n = sqrtf(L[0]*L[0] + L[1]*L[1] + L[2]*L[2] + L[3]*L[3] + L[4]*L[4] + L[5]*L[5]);
    float inv = 1.f / fmaxf(n, 1e-12f);
    #pragma unroll
    for (int p = 0; p < 6; ++p) L[p] *= inv;
}

// outputs: rlb/jwb bf16 [12][2048][8] (6 real + 2 zero pad), gate fp32 [2048]
__global__ __launch_bounds__(256) void smallproj_kernel(
    const __hip_bfloat16* __restrict__ ln1,
    const float* __restrict__ w1w, const float* __restrict__ w2w,
    const float* __restrict__ w1r, const float* __restrict__ w2r,
    const float* __restrict__ gw, const float* __restrict__ gb,
    __hip_bfloat16* __restrict__ rlb, __hip_bfloat16* __restrict__ jwb,
    float* __restrict__ gate)
{
    const int t = blockIdx.x;
    const int tid = threadIdx.x;
    __shared__ float xc[768], xp[768], res[204];
    const __hip_bfloat16* cur = ln1 + (size_t)t * DD;
    #pragma unroll
    for (int i = 0; i < 3; ++i) {
        int idx = tid + (i << 8);
        xc[idx] = __bfloat162float(cur[idx]);
        xp[idx] = (t > 0) ? __bfloat162float(cur[idx - DD]) : 0.f;
    }
    __syncthreads();
    if (tid < 204) {
        const float* wsel; const float* xv; int col, stride;
        if (tid < 48)       { wsel = w2w; xv = xc; col = tid;       stride = 48; }
        else if (tid < 96)  { wsel = w1w; xv = xp; col = tid - 48;  stride = 48; }
        else if (tid < 144) { wsel = w1r; xv = xc; col = tid - 96;  stride = 48; }
        else if (tid < 192) { wsel = w2r; xv = xc; col = tid - 144; stride = 48; }
        else                { wsel = gw;  xv = xc; col = tid - 192; stride = 12; }
        float s = 0.f;
        for (int k = 0; k < 768; ++k) s += xv[k] * wsel[(size_t)k * stride + col];
        if (tid >= 192) s += gb[col];
        res[tid] = s;
    }
    __syncthreads();
    if (tid < 12) {
        const int h = tid;
        float a[4], b[4], L[6];
        // write lines: exterior(w1(x_prev), w2(x)) then J6 = [L5,-L4,L3,L2,-L1,L0]
        #pragma unroll
        for (int i = 0; i < 4; ++i) { a[i] = res[48 + h * 4 + i]; b[i] = res[h * 4 + i]; }
        exterior6(a, b, L);
        __hip_bfloat16* jwp = jwb + (size_t)h * 16384 + t * 8;
        jwp[0] = __float2bfloat16( L[5]); jwp[1] = __float2bfloat16(-L[4]);
        jwp[2] = __float2bfloat16( L[3]); jwp[3] = __float2bfloat16( L[2]);
        jwp[4] = __float2bfloat16(-L[1]); jwp[5] = __float2bfloat16( L[0]);
        jwp[6] = __float2bfloat16(0.f);   jwp[7] = __float2bfloat16(0.f);
        // read lines: exterior(r1, r2)
        #pragma unroll
        for (int i = 0; i < 4; ++i) { a[i] = res[96 + h * 4 + i]; b[i] = res[144 + h * 4 + i]; }
        exterior6(a, b, L);
        __hip_bfloat16* rlp = rlb + (size_t)h * 16384 + t * 8;
        #pragma unroll
        for (int p = 0; p < 6; ++p) rlp[p] = __float2bfloat16(L[p]);
        rlp[6] = __float2bfloat16(0.f); rlp[7] = __float2bfloat16(0.f);
    }
    if (tid == 0) {
        float g = 0.f;
        #pragma unroll
        for (int i = 0; i < 12; ++i) g += 1.f / (1.f + __expf(-res[192 + i]));
        gate[t] = g * (1.f / 12.f);
    }
}

// ------------------------------------------- per-head transpose: V/GV -> VT[h][64][2048]
__global__ __launch_bounds__(256) void vt_kernel(
    const __hip_bfloat16* __restrict__ qkvB, const __hip_bfloat16* __restrict__ geovB,
    __hip_bfloat16* __restrict__ VT, __hip_bfloat16* __restrict__ GVT)
{
    __shared__ __hip_bfloat16 tile[64][72];
    const int s0 = blockIdx.x << 6, h = blockIdx.y;
    const bool isGV = (blockIdx.z != 0);
    const __hip_bfloat16* src = isGV ? (geovB + h * 64) : (qkvB + 1536 + h * 64);
    const int stride = isGV ? 768 : 2304;
    __hip_bfloat16* dst = (isGV ? GVT : VT) + (size_t)h * 131072;
    const int tid = threadIdx.x;
    const int r = tid >> 2, c = (tid & 3) << 3;
    *(bf16x8*)&tile[r][c]      = *(const bf16x8*)&src[(size_t)(s0 + r) * stride + c];
    *(bf16x8*)&tile[r][c + 32] = *(const bf16x8*)&src[(size_t)(s0 + r) * stride + c + 32];
    __syncthreads();
    __hip_bfloat16 tmp[8];
    #pragma unroll
    for (int j = 0; j < 8; ++j) tmp[j] = tile[c + j][r];
    *(bf16x8*)&dst[(size_t)r * 2048 + s0 + c] = *(const bf16x8*)tmp;
    #pragma unroll
    for (int j = 0; j < 8; ++j) tmp[j] = tile[c + 32 + j][r];
    *(bf16x8*)&dst[(size_t)r * 2048 + s0 + c + 32] = *(const bf16x8*)tmp;
}

// ---------------------------------------------------------------- MFMA dual-path flash attention
// Balanced K-split: job j (per head) -> (qt, chunk c of nc) with
// nc = 1 (qt<12) / 2 (qt<24) / 3 (qt>=24); chunk covers k-tiles
// [c*nk/nc, (c+1)*nk/nc). 4 waves, 64-row q tile, LDS-staged tiles,
// register prefetch. nc==1 writes comb; else unnormalized partials + stats.
__global__ __launch_bounds__(256) void mattn_kernel(
    const __hip_bfloat16* __restrict__ qkvB, const __hip_bfloat16* __restrict__ VT,
    const __hip_bfloat16* __restrict__ GVT, const __hip_bfloat16* __restrict__ rlb,
    const __hip_bfloat16* __restrict__ jwb, const float* __restrict__ gate,
    const float* __restrict__ inc_scale, __hip_bfloat16* __restrict__ comb,
    __hip_bfloat16* __restrict__ Opart, float* __restrict__ stats)
{
    __shared__ __hip_bfloat16 Ks[64][72];    // [s][d]
    __shared__ __hip_bfloat16 VTs[64][72];   // [d][s]
    __shared__ __hip_bfloat16 GVTs[64][72];  // [d][s]
    __shared__ __hip_bfloat16 JWs[64][8];    // [s][p(6+2pad)]
    __shared__ __bf16 Ps[64][72];            // P std [q][s]
    __shared__ __bf16 Pg[64][72];            // P geo

    const int j = 59 - blockIdx.x;           // longest jobs dispatch first
    const int hh = blockIdx.y;
    int qt, c, nc;
    if (j < 12)      { qt = j; c = 0; nc = 1; }
    else if (j < 36) { int t2 = j - 12; qt = 12 + (t2 >> 1); c = t2 & 1; nc = 2; }
    else             { int t2 = j - 36; int d3 = t2 / 3; qt = 24 + d3; c = t2 - d3 * 3; nc = 3; }
    const int q0 = qt << 6;
    const int nk = qt + 1;
    const int ktb = c * nk / nc;
    const int kte = (c + 1) * nk / nc - 1;
    const int tid = threadIdx.x;
    const int w = tid >> 6, lane = tid & 63;
    const int n = lane & 15, quad = lane >> 4;

    // Q fragments (A-layout: lane m=n holds row q0+16w+n, k=quad*8+jj)
    const int qrow = q0 + (w << 4) + n;
    const size_t qb = (size_t)qrow * 2304 + hh * 64;
    bf16x8 af0 = *(const bf16x8*)&qkvB[qb + (quad << 3)];
    bf16x8 af1 = *(const bf16x8*)&qkvB[qb + 32 + (quad << 3)];
    bf16x8 rlA = zero8();
    if (quad == 0) rlA = *(const bf16x8*)&rlb[(size_t)hh * 16384 + (size_t)qrow * 8];
    const float isc = inc_scale[hh];
    const size_t vbase = (size_t)hh * 131072;

    const int sRow = tid >> 2, sChk = (tid & 3) << 3;   // cols sChk, sChk+32

    f32x4 Os[4], Og[4];
    float m_s[4], l_s[4], m_g[4], l_g[4];
    #pragma unroll
    for (int r = 0; r < 4; ++r) {
        m_s[r] = -1e30f; l_s[r] = 0.f; m_g[r] = -1e30f; l_g[r] = 0.f;
        Os[r] = (f32x4){0.f, 0.f, 0.f, 0.f};
        Og[r] = (f32x4){0.f, 0.f, 0.f, 0.f};
    }

    // prefetch first tile into registers
    bf16x8 rK0, rK1, rV0, rV1, rG0, rG1, rJ = zero8();
    {
        const int k0 = ktb << 6;
        const size_t kb = (size_t)(k0 + sRow) * 2304 + 768 + hh * 64;
        const size_t vb = vbase + (size_t)sRow * 2048 + k0;
        rK0 = *(const bf16x8*)&qkvB[kb + sChk];
        rK1 = *(const bf16x8*)&qkvB[kb + sChk + 32];
        rV0 = *(const bf16x8*)&VT[vb + sChk];
        rV1 = *(const bf16x8*)&VT[vb + sChk + 32];
        rG0 = *(const bf16x8*)&GVT[vb + sChk];
        rG1 = *(const bf16x8*)&GVT[vb + sChk + 32];
        if (tid < 64) rJ = *(const bf16x8*)&jwb[(size_t)hh * 16384 + (size_t)(k0 + tid) * 8];
    }

    for (int kt = ktb; kt <= kte; ++kt) {
        const int k0 = kt << 6;
        __syncthreads();   // prior reads of LDS tiles done
        *(bf16x8*)&Ks[sRow][sChk]        = rK0;
        *(bf16x8*)&Ks[sRow][sChk + 32]   = rK1;
        *(bf16x8*)&VTs[sRow][sChk]       = rV0;
        *(bf16x8*)&VTs[sRow][sChk + 32]  = rV1;
        *(bf16x8*)&GVTs[sRow][sChk]      = rG0;
        *(bf16x8*)&GVTs[sRow][sChk + 32] = rG1;
        if (tid < 64) *(bf16x8*)&JWs[tid][0] = rJ;
        if (kt < kte) {
            const int k1 = (kt + 1) << 6;
            const size_t kb = (size_t)(k1 + sRow) * 2304 + 768 + hh * 64;
            const size_t vb = vbase + (size_t)sRow * 2048 + k1;
            rK0 = *(const bf16x8*)&qkvB[kb + sChk];
            rK1 = *(const bf16x8*)&qkvB[kb + sChk + 32];
            rV0 = *(const bf16x8*)&VT[vb + sChk];
            rV1 = *(const bf16x8*)&VT[vb + sChk + 32];
            rG0 = *(const bf16x8*)&GVT[vb + sChk];
            rG1 = *(const bf16x8*)&GVT[vb + sChk + 32];
            if (tid < 64) rJ = *(const bf16x8*)&jwb[(size_t)hh * 16384 + (size_t)(k1 + tid) * 8];
        }
        __syncthreads();   // LDS tiles ready

        // ---- S = QK^T (std) and RL·JW (geo), 4 col-tiles of 16
        f32x4 Ss[4], Sg[4];
        #pragma unroll
        for (int t = 0; t < 4; ++t) {
            Ss[t] = (f32x4){0.f, 0.f, 0.f, 0.f};
            Sg[t] = (f32x4){0.f, 0.f, 0.f, 0.f};
        }
        #pragma unroll
        for (int t = 0; t < 4; ++t) {
            bf16x8 kb0 = *(const bf16x8*)&Ks[(t << 4) + n][(quad << 3)];
            bf16x8 kb1 = *(const bf16x8*)&Ks[(t << 4) + n][32 + (quad << 3)];
            Ss[t] = __builtin_amdgcn_mfma_f32_16x16x32_bf16(af0, kb0, Ss[t], 0, 0, 0);
            Ss[t] = __builtin_amdgcn_mfma_f32_16x16x32_bf16(af1, kb1, Ss[t], 0, 0, 0);
            bf16x8 jb = zero8();
            if (quad == 0) jb = *(const bf16x8*)&JWs[(t << 4) + n][0];
            Sg[t] = __builtin_amdgcn_mfma_f32_16x16x32_bf16(rlA, jb, Sg[t], 0, 0, 0);
        }
        // scale + causal mask (diagonal k-tile only; lives in the last chunk)
        #pragma unroll
        for (int t = 0; t < 4; ++t) {
            #pragma unroll
            for (int r = 0; r < 4; ++r) { Ss[t][r] *= 0.125f; Sg[t][r] *= isc; }
        }
        if (kt == qt) {
            #pragma unroll
            for (int t = 0; t < 4; ++t) {
                const int sg = k0 + (t << 4) + n;
                #pragma unroll
                for (int r = 0; r < 4; ++r) {
                    const int qg = q0 + (w << 4) + (quad << 2) + r;
                    if (sg > qg) { Ss[t][r] = -1e30f; Sg[t][r] = -1e30f; }
                }
            }
        }

        // ---- online softmax, both paths; Ss/Sg -> probabilities
        #pragma unroll
        for (int r = 0; r < 4; ++r) {
            float mx = fmaxf(fmaxf(Ss[0][r], Ss[1][r]), fmaxf(Ss[2][r], Ss[3][r]));
            #pragma unroll
            for (int mk = 1; mk < 16; mk <<= 1) mx = fmaxf(mx, __shfl_xor(mx, mk));
            float mnew = fmaxf(m_s[r], mx);
            float alpha = __expf(m_s[r] - mnew);
            m_s[r] = mnew;
            float sm = 0.f;
            #pragma unroll
            for (int t = 0; t < 4; ++t) { Ss[t][r] = __expf(Ss[t][r] - mnew); sm += Ss[t][r]; }
            #pragma unroll
            for (int mk = 1; mk < 16; mk <<= 1) sm += __shfl_xor(sm, mk);
            l_s[r] = l_s[r] * alpha + sm;
            #pragma unroll
            for (int t = 0; t < 4; ++t) Os[t][r] *= alpha;

            float mxg = fmaxf(fmaxf(Sg[0][r], Sg[1][r]), fmaxf(Sg[2][r], Sg[3][r]));
            #pragma unroll
            for (int mk = 1; mk < 16; mk <<= 1) mxg = fmaxf(mxg, __shfl_xor(mxg, mk));
            float mnewg = fmaxf(m_g[r], mxg);
            float alphag = __expf(m_g[r] - mnewg);
            m_g[r] = mnewg;
            float smg = 0.f;
            #pragma unroll
            for (int t = 0; t < 4; ++t) { Sg[t][r] = __expf(Sg[t][r] - mnewg); smg += Sg[t][r]; }
            #pragma unroll
            for (int mk = 1; mk < 16; mk <<= 1) smg += __shfl_xor(smg, mk);
            l_g[r] = l_g[r] * alphag + smg;
            #pragma unroll
            for (int t = 0; t < 4; ++t) Og[t][r] *= alphag;
        }

        // ---- P -> LDS (C-layout), fence, then PV A-fragment reads
        #pragma unroll
        for (int t = 0; t < 4; ++t) {
            #pragma unroll
            for (int r = 0; r < 4; ++r) {
                Ps[(w << 4) + (quad << 2) + r][(t << 4) + n] = (__bf16)Ss[t][r];
                Pg[(w << 4) + (quad << 2) + r][(t << 4) + n] = (__bf16)Sg[t][r];
            }
        }
        __syncthreads();   // P stores visible before PV fragment loads

        // ---- PV for both paths: Os[dt] += P · V, Og[dt] += Pg · GV
        #pragma unroll
        for (int st = 0; st < 2; ++st) {
            bf16x8 ap = *(const bf16x8*)&Ps[(w << 4) + n][(st << 5) + (quad << 3)];
            bf16x8 gp = *(const bf16x8*)&Pg[(w << 4) + n][(st << 5) + (quad << 3)];
            #pragma unroll
            for (int dt = 0; dt < 4; ++dt) {
                bf16x8 vb2 = *(const bf16x8*)&VTs[(dt << 4) + n][(st << 5) + (quad << 3)];
                bf16x8 gb2 = *(const bf16x8*)&GVTs[(dt << 4) + n][(st << 5) + (quad << 3)];
                Os[dt] = __builtin_amdgcn_mfma_f32_16x16x32_bf16(ap, vb2, Os[dt], 0, 0, 0);
                Og[dt] = __builtin_amdgcn_mfma_f32_16x16x32_bf16(gp, gb2, Og[dt], 0, 0, 0);
            }
        }
    }

    if (nc == 1) {
        // ---- direct epilogue: combine with gate, write bf16
        #pragma unroll
        for (int r = 0; r < 4; ++r) {
            const int row = q0 + (w << 4) + (quad << 2) + r;
            const float g = gate[row];
            const float invs = (1.f - g) / l_s[r], invg = g / l_g[r];
            #pragma unroll
            for (int dt = 0; dt < 4; ++dt) {
                float val = Os[dt][r] * invs + Og[dt][r] * invg;
                comb[(size_t)row * DD + hh * 64 + (dt << 4) + n] = __float2bfloat16(val);
            }
        }
    } else {
        // ---- partial epilogue: unnormalized O (bf16) + per-row stats
        const int base = (qt < 24) ? ((qt - 12) << 1) : (24 + (qt - 24) * 3);
        const int slot = hh * 48 + base + c;
        __hip_bfloat16* op = Opart + (size_t)slot * 8192;    // [row64][path2*col64]
        float* st = stats + (size_t)slot * 256;               // [row64][4]
        #pragma unroll
        for (int r = 0; r < 4; ++r) {
            const int rloc = (w << 4) + (quad << 2) + r;
            #pragma unroll
            for (int dt = 0; dt < 4; ++dt) {
                const int col = (dt << 4) + n;
                op[rloc * 128 + col]      = __float2bfloat16(Os[dt][r]);
                op[rloc * 128 + 64 + col] = __float2bfloat16(Og[dt][r]);
            }
            if (n == 0) {
                st[rloc * 4 + 0] = m_s[r]; st[rloc * 4 + 1] = l_s[r];
                st[rloc * 4 + 2] = m_g[r]; st[rloc * 4 + 3] = l_g[r];
            }
        }
    }
}

// ------------------------------------------- combine 2-3 K-chunks (qt>=12)
__global__ __launch_bounds__(256) void acomb_kernel(
    const __hip_bfloat16* __restrict__ Opart, const float* __restrict__ stats,
    const float* __restrict__ gate, __hip_bfloat16* __restrict__ comb)
{
    const int qt = 12 + blockIdx.x;          // 12..31
    const int h = blockIdx.y;
    const int nc = (qt < 24) ? 2 : 3;
    const int sb = h * 48 + ((qt < 24) ? ((qt - 12) << 1) : (24 + (qt - 24) * 3));
    const int tid = threadIdx.x;
    const int rloc = tid >> 2;               // 0..63
    const int cseg = (tid & 3) << 4;         // 16 cols per thread
    const int row = (qt << 6) + rloc;
    float ms = -1e30f, mg = -1e30f;
    for (int c = 0; c < nc; ++c) {
        const float* st = stats + (size_t)(sb + c) * 256 + rloc * 4;
        ms = fmaxf(ms, st[0]);
        mg = fmaxf(mg, st[2]);
    }
    float wsc[3], wgc[3];
    float ls = 0.f, lg = 0.f;
    for (int c = 0; c < nc; ++c) {
        const float* st = stats + (size_t)(sb + c) * 256 + rloc * 4;
        wsc[c] = __expf(st[0] - ms); ls += st[1] * wsc[c];
        wgc[c] = __expf(st[2] - mg); lg += st[3] * wgc[c];
    }
    const float g = gate[row];
    const float fs = (1.f - g) / ls, fg = g / lg;
    #pragma unroll
    for (int cc = 0; cc < 16; ++cc) {
        const int col = cseg + cc;
        float os = 0.f, og = 0.f;
        for (int c = 0; c < nc; ++c) {
            const __hip_bfloat16* op = Opart + (size_t)(sb + c) * 8192 + rloc * 128;
            os += __bfloat162float(op[col]) * wsc[c];
            og += __bfloat162float(op[64 + col]) * wgc[c];
        }
        comb[(size_t)row * DD + h * 64 + col] = __float2bfloat16(os * fs + og * fg);
    }
}

// ---------------------------------------------------------------- launch
extern "C" void kernel_launch(void* const* d_in, const int* in_sizes, int n_in,
                              void* d_out, int out_size, void* d_ws, size_t ws_size,
                              hipStream_t stream) {
    (void)in_sizes; (void)n_in; (void)out_size; (void)ws_size;
    const float* x      = (const float*)d_in[0];
    const float* ln1_g  = (const float*)d_in[1];
    const float* ln1_b  = (const float*)d_in[2];
    const float* qkv_w  = (const float*)d_in[3];
    const float* qkv_b  = (const float*)d_in[4];
    const float* w1w    = (const float*)d_in[5];
    const float* w2w    = (const float*)d_in[6];
    const float* w1r    = (const float*)d_in[7];
    const float* w2r    = (const float*)d_in[8];
    const float* gvw    = (const float*)d_in[9];
    const float* gvb    = (const float*)d_in[10];
    const float* gw     = (const float*)d_in[11];
    const float* gb     = (const float*)d_in[12];
    const float* isc    = (const float*)d_in[13];
    const float* ow     = (const float*)d_in[14];
    const float* ob     = (const float*)d_in[15];
    const float* ln2_g  = (const float*)d_in[16];
    const float* ln2_b  = (const float*)d_in[17];
    const float* fcw    = (const float*)d_in[18];
    const float* fcb    = (const float*)d_in[19];
    const float* pw     = (const float*)d_in[20];
    const float* pb     = (const float*)d_in[21];
    float* out = (float*)d_out;
    char* wsb  = (char*)d_ws;

    // workspace layout (bytes), total ~38.7 MB
    __hip_bfloat16* qkvB  = (__hip_bfloat16*)(wsb + 0);          //  9,437,184 bf16 [2048,2304]
    __hip_bfloat16* geovB = (__hip_bfloat16*)(wsb + 9437184);    //  3,145,728 bf16 [2048,768]
    __hip_bfloat16* VTb   = (__hip_bfloat16*)(wsb + 12582912);   //  3,145,728 bf16 [12][64][2048]
    __hip_bfloat16* GVTb  = (__hip_bfloat16*)(wsb + 15728640);   //  3,145,728
    __hip_bfloat16* rlb   = (__hip_bfloat16*)(wsb + 18874368);   //    393,216 bf16 [12][2048][8]
    __hip_bfloat16* jwb   = (__hip_bfloat16*)(wsb + 19267584);   //    393,216
    float*          gate  = (float*)(wsb + 19660800);            //      8,192
    __hip_bfloat16* ln1   = (__hip_bfloat16*)(wsb + 19668992);   //  3,145,728 (reused for ln2)
    __hip_bfloat16* comb  = (__hip_bfloat16*)(wsb + 22814720);   //  3,145,728
    float*          hbuf  = (float*)(wsb + 25960448);            //  6,291,456 fp32 [2048,768]
    __hip_bfloat16* qkvwt = (__hip_bfloat16*)(wsb + 32251904);   //  3,538,944 bf16 [2304,768]
    __hip_bfloat16* gvwt  = (__hip_bfloat16*)(wsb + 35790848);   //  1,179,648 bf16 [768,768]
    __hip_bfloat16* owt   = (__hip_bfloat16*)(wsb + 36970496);   //  1,179,648 bf16 [768,768]
    float*          stats = (float*)(wsb + 38150144);            //    589,824 fp32 [576][64][4]
    // attention partials: 576 slots x 16KB, overlaying hbuf + qkvwt regions
    // (both dead during mattn/acomb; rewritten after):
    __hip_bfloat16* Opart = (__hip_bfloat16*)hbuf;
    // reuse (producers dead by then):
    __hip_bfloat16* fcwt  = qkvwt;                               //  4,718,592 [3072,768]
    __hip_bfloat16* pwt   = (__hip_bfloat16*)(wsb + 0);          //  4,718,592 [768,3072]
    __hip_bfloat16* fcact = (__hip_bfloat16*)(wsb + 4718592);    // 12,582,912 [2048,3072]
    // proj split-K fp32 partials (dead regions during proj):
    float* Ppart0 = (float*)(wsb + 18874368);   // 6,291,456 (rlb..comb-start; all dead)
    float* Ppart1 = (float*)(wsb + 32251904);   // 6,291,456 (fcwt/gvwt/owt+stats; dead)

    castT_kernel<<<dim3(72, 24), 256, 0, stream>>>(qkv_w, qkvwt, 768, 2304);
    castT_kernel<<<dim3(24, 24), 256, 0, stream>>>(gvw, gvwt, 768, 768);
    ln_kernel<<<TT, 256, 0, stream>>>(x, ln1_g, ln1_b, ln1);
    mgemm64_kernel<<<dim3(18, 32, 1), 256, 0, stream>>>(ln1, qkvwt, qkv_b, nullptr, qkvB, nullptr, nullptr, TT, 2304, 768, 1, 0, 1);
    mgemm64_kernel<<<dim3(6, 32, 1), 256, 0, stream>>>(ln1, gvwt, gvb, nullptr, geovB, nullptr, nullptr, TT, 768, 768, 1, 0, 1);
    vt_kernel<<<dim3(32, 12, 2), 256, 0, stream>>>(qkvB, geovB, VTb, GVTb);
    smallproj_kernel<<<TT, 256, 0, stream>>>(ln1, w1w, w2w, w1r, w2r, gw, gb, rlb, jwb, gate);
    mattn_kernel<<<dim3(60, 12), 256, 0, stream>>>(qkvB, VTb, GVTb, rlb, jwb, gate, isc, comb, Opart, stats);
    acomb_kernel<<<dim3(20, 12), 256, 0, stream>>>(Opart, stats, gate, comb);
    castT_kernel<<<dim3(24, 24), 256, 0, stream>>>(ow, owt, 768, 768);
    mgemm64_kernel<<<dim3(6, 32, 1), 256, 0, stream>>>(comb, owt, ob, x, hbuf, nullptr, nullptr, TT, 768, 768, 1, 2, 0);
    ln_kernel<<<TT, 256, 0, stream>>>(hbuf, ln2_g, ln2_b, ln1);
    castT_kernel<<<dim3(96, 24), 256, 0, stream>>>(fcw, fcwt, 768, 3072);
    mgemm64_kernel<<<dim3(24, 32, 1), 256, 0, stream>>>(ln1, fcwt, fcb, nullptr, fcact, nullptr, nullptr, TT, 3072, 768, 1, 1, 1);
    castT_kernel<<<dim3(24, 96), 256, 0, stream>>>(pw, pwt, 3072, 768);
    mgemm64_kernel<<<dim3(6, 32, 2), 256, 0, stream>>>(fcact, pwt, pb, nullptr, nullptr, Ppart0, Ppart1, TT, 768, 3072, 2, 0, 0);
    kred_kernel<<<1536, 256, 0, stream>>>(Ppart0, Ppart1, pb, hbuf, out, 768);
}

// Round 12
// 401.797 us; speedup vs baseline: 1.2975x; 1.0264x over previous
//
#include <hip/hip_runtime.h>
#include <hip/hip_bf16.h>
#include <math.h>

#define TT 2048
#define DD 768

typedef __bf16 bf16x8 __attribute__((ext_vector_type(8)));
typedef float f32x4 __attribute__((ext_vector_type(4)));

__device__ __forceinline__ void gload16(const void* g, void* l) {
    __builtin_amdgcn_global_load_lds(
        (const __attribute__((address_space(1))) unsigned int*)g,
        (__attribute__((address_space(3))) unsigned int*)l, 16, 0, 0);
}

__device__ __forceinline__ bf16x8 zero8() {
    bf16x8 v;
    #pragma unroll
    for (int j = 0; j < 8; ++j) v[j] = (__bf16)0.0f;
    return v;
}

// ---------------------------------------------------------------- LayerNorm (fp32 in -> bf16 out)
__global__ __launch_bounds__(256) void ln_kernel(const float* __restrict__ in,
    const float* __restrict__ g, const float* __restrict__ b,
    __hip_bfloat16* __restrict__ out)
{
    const int t = blockIdx.x;
    const int tid = threadIdx.x;
    const float* row = in + (size_t)t * DD;
    float x0 = row[tid], x1 = row[tid + 256], x2 = row[tid + 512];
    float s = x0 + x1 + x2;
    float q = x0 * x0 + x1 * x1 + x2 * x2;
    #pragma unroll
    for (int m = 1; m < 64; m <<= 1) {
        s += __shfl_xor(s, m);
        q += __shfl_xor(q, m);
    }
    __shared__ float ssum[4], sqsum[4];
    const int w = tid >> 6;
    if ((tid & 63) == 0) { ssum[w] = s; sqsum[w] = q; }
    __syncthreads();
    s = ssum[0] + ssum[1] + ssum[2] + ssum[3];
    q = sqsum[0] + sqsum[1] + sqsum[2] + sqsum[3];
    const float mean = s * (1.0f / DD);
    const float var = q * (1.0f / DD) - mean * mean;
    const float rs = rsqrtf(var + 1e-5f);
    __hip_bfloat16* orow = out + (size_t)t * DD;
    orow[tid]       = __float2bfloat16((x0 - mean) * rs * g[tid]       + b[tid]);
    orow[tid + 256] = __float2bfloat16((x1 - mean) * rs * g[tid + 256] + b[tid + 256]);
    orow[tid + 512] = __float2bfloat16((x2 - mean) * rs * g[tid + 512] + b[tid + 512]);
}

// ------------------------------------------- transpose + cast: fp32 [K,N] -> bf16 [N,K]
__global__ __launch_bounds__(256) void castT_kernel(const float* __restrict__ in,
    __hip_bfloat16* __restrict__ out, int K, int N)
{
    __shared__ float t[32][33];
    const int n0 = blockIdx.x << 5, k0 = blockIdx.y << 5;
    const int tx = threadIdx.x & 31, ty = threadIdx.x >> 5;
    #pragma unroll
    for (int i = 0; i < 32; i += 8)
        t[ty + i][tx] = in[(size_t)(k0 + ty + i) * N + n0 + tx];
    __syncthreads();
    #pragma unroll
    for (int i = 0; i < 32; i += 8)
        out[(size_t)(n0 + ty + i) * K + k0 + tx] = __float2bfloat16(t[tx][ty + i]);
}

// ---------------------------------------------------------------- MFMA GEMM (64x128 tile)
__device__ __forceinline__ float gelu_f(float x) {
    float u = 0.7978845608028654f * (x + 0.044715f * x * x * x);
    return 0.5f * x * (1.0f + tanhf(u));
}

__global__ __launch_bounds__(256) void mgemm64_kernel(
    const __hip_bfloat16* __restrict__ A, const __hip_bfloat16* __restrict__ Bt,
    const float* __restrict__ bias, const float* __restrict__ resid,
    void* __restrict__ Cout, float* __restrict__ Pb0, float* __restrict__ Pb1,
    int M, int N, int K, int kz, int epi, int omode)
{
    __shared__ __hip_bfloat16 As[64 * 32];
    __shared__ __hip_bfloat16 Bs[128 * 32];
    const int tid = threadIdx.x;
    const int lane = tid & 63, w = tid >> 6;
    const int colBase = blockIdx.x << 7, rowBase = blockIdx.y << 6;
    const int z = blockIdx.z;
    const int Kc = K / kz, koff = z * Kc;

    const int lr = lane >> 2, pc = lane & 3;
    const int n = lane & 15, quad = lane >> 4;

    const int arow = (w << 4) + lr;
    const int ac = (pc ^ ((arow >> 1) & 3)) << 3;
    const int brow0 = (w << 5) + lr, brow1 = brow0 + 16;
    const int bc0 = (pc ^ ((brow0 >> 1) & 3)) << 3;
    const int bc1 = (pc ^ ((brow1 >> 1) & 3)) << 3;

    f32x4 acc[8];
    #pragma unroll
    for (int j = 0; j < 8; ++j) acc[j] = (f32x4){0.f, 0.f, 0.f, 0.f};

    const int arF = (w << 4) + n;
    const int aposF = (quad ^ ((arF >> 1) & 3)) << 3;

    for (int kk = koff; kk < koff + Kc; kk += 32) {
        __syncthreads();
        gload16(A  + (size_t)(rowBase + arow) * K + kk + ac,   &As[(w << 4) * 32]);
        gload16(Bt + (size_t)(colBase + brow0) * K + kk + bc0, &Bs[(w << 5) * 32]);
        gload16(Bt + (size_t)(colBase + brow1) * K + kk + bc1, &Bs[((w << 5) + 16) * 32]);
        __syncthreads();

        bf16x8 af = *(const bf16x8*)&As[arF * 32 + aposF];
        #pragma unroll
        for (int j = 0; j < 8; ++j) {
            const int rb = (j << 4) + n;
            bf16x8 bfj = *(const bf16x8*)&Bs[rb * 32 + ((quad ^ ((rb >> 1) & 3)) << 3)];
            acc[j] = __builtin_amdgcn_mfma_f32_16x16x32_bf16(af, bfj, acc[j], 0, 0, 0);
        }
    }

    if (kz == 1) {
        #pragma unroll
        for (int j = 0; j < 8; ++j) {
            const int col = colBase + (j << 4) + n;
            const float bj = bias[col];
            #pragma unroll
            for (int r = 0; r < 4; ++r) {
                const int row = rowBase + (w << 4) + (quad << 2) + r;
                float v = acc[j][r] + bj;
                if (epi == 1) v = gelu_f(v);
                else if (epi == 2) v += resid[(size_t)row * N + col];
                if (omode == 1) ((__hip_bfloat16*)Cout)[(size_t)row * N + col] = __float2bfloat16(v);
                else ((float*)Cout)[(size_t)row * N + col] = v;
            }
        }
    } else {
        float* P = (z == 0) ? Pb0 : Pb1;
        #pragma unroll
        for (int j = 0; j < 8; ++j) {
            const int col = colBase + (j << 4) + n;
            #pragma unroll
            for (int r = 0; r < 4; ++r) {
                const int row = rowBase + (w << 4) + (quad << 2) + r;
                P[(size_t)row * N + col] = acc[j][r];
            }
        }
    }
}

// ------------------------------------------- split-K reduce: out = p0+p1+bias+resid (fp32)
__global__ __launch_bounds__(256) void kred_kernel(
    const float* __restrict__ p0, const float* __restrict__ p1,
    const float* __restrict__ bias, const float* __restrict__ resid,
    float* __restrict__ out, int N)
{
    const int base = (blockIdx.x * 256 + threadIdx.x) << 2;
    float4 a = *(const float4*)&p0[base];
    float4 b = *(const float4*)&p1[base];
    float4 bi = *(const float4*)&bias[base % N];
    float4 rs = *(const float4*)&resid[base];
    float4 o;
    o.x = a.x + b.x + bi.x + rs.x;
    o.y = a.y + b.y + bi.y + rs.y;
    o.z = a.z + b.z + bi.z + rs.z;
    o.w = a.w + b.w + bi.w + rs.w;
    *(float4*)&out[base] = o;
}

// ------------------------------------------------- small projections + exterior
__device__ __forceinline__ void exterior6(const float* a, const float* b, float* L) {
    L[0] = a[0] * b[1] - a[1] * b[0];
    L[1] = a[0] * b[2] - a[2] * b[0];
    L[2] = a[0] * b[3] - a[3] * b[0];
    L[3] = a[1] * b[2] - a[2] * b[1];
    L[4] = a[1] * b[3] - a[3] * b[1];
    L[5] = a[2] * b[3] - a[3] * b[2];
    float n = sqrtf(L[0]*L[0] + L[1]*L[1] + L[2]*L[2] + L[3]*L[3] + L[4]*L[4] + L[5]*L[5]);
    float inv = 1.f / fmaxf(n, 1e-12f);
    #pragma unroll
    for (int p = 0; p < 6; ++p) L[p] *= inv;
}

// outputs: rlb/jwb bf16 [12][2048][8] (6 real + 2 zero pad), gate fp32 [2048]
__global__ __launch_bounds__(256) void smallproj_kernel(
    const __hip_bfloat16* __restrict__ ln1,
    const float* __restrict__ w1w, const float* __restrict__ w2w,
    const float* __restrict__ w1r, const float* __restrict__ w2r,
    const float* __restrict__ gw, const float* __restrict__ gb,
    __hip_bfloat16* __restrict__ rlb, __hip_bfloat16* __restrict__ jwb,
    float* __restrict__ gate)
{
    const int t = blockIdx.x;
    const int tid = threadIdx.x;
    __shared__ float xc[768], xp[768], res[204];
    const __hip_bfloat16* cur = ln1 + (size_t)t * DD;
    #pragma unroll
    for (int i = 0; i < 3; ++i) {
        int idx = tid + (i << 8);
        xc[idx] = __bfloat162float(cur[idx]);
        xp[idx] = (t > 0) ? __bfloat162float(cur[idx - DD]) : 0.f;
    }
    __syncthreads();
    if (tid < 204) {
        const float* wsel; const float* xv; int col, stride;
        if (tid < 48)       { wsel = w2w; xv = xc; col = tid;       stride = 48; }
        else if (tid < 96)  { wsel = w1w; xv = xp; col = tid - 48;  stride = 48; }
        else if (tid < 144) { wsel = w1r; xv = xc; col = tid - 96;  stride = 48; }
        else if (tid < 192) { wsel = w2r; xv = xc; col = tid - 144; stride = 48; }
        else                { wsel = gw;  xv = xc; col = tid - 192; stride = 12; }
        float s = 0.f;
        for (int k = 0; k < 768; ++k) s += xv[k] * wsel[(size_t)k * stride + col];
        if (tid >= 192) s += gb[col];
        res[tid] = s;
    }
    __syncthreads();
    if (tid < 12) {
        const int h = tid;
        float a[4], b[4], L[6];
        #pragma unroll
        for (int i = 0; i < 4; ++i) { a[i] = res[48 + h * 4 + i]; b[i] = res[h * 4 + i]; }
        exterior6(a, b, L);
        __hip_bfloat16* jwp = jwb + (size_t)h * 16384 + t * 8;
        jwp[0] = __float2bfloat16( L[5]); jwp[1] = __float2bfloat16(-L[4]);
        jwp[2] = __float2bfloat16( L[3]); jwp[3] = __float2bfloat16( L[2]);
        jwp[4] = __float2bfloat16(-L[1]); jwp[5] = __float2bfloat16( L[0]);
        jwp[6] = __float2bfloat16(0.f);   jwp[7] = __float2bfloat16(0.f);
        #pragma unroll
        for (int i = 0; i < 4; ++i) { a[i] = res[96 + h * 4 + i]; b[i] = res[144 + h * 4 + i]; }
        exterior6(a, b, L);
        __hip_bfloat16* rlp = rlb + (size_t)h * 16384 + t * 8;
        #pragma unroll
        for (int p = 0; p < 6; ++p) rlp[p] = __float2bfloat16(L[p]);
        rlp[6] = __float2bfloat16(0.f); rlp[7] = __float2bfloat16(0.f);
    }
    if (tid == 0) {
        float g = 0.f;
        #pragma unroll
        for (int i = 0; i < 12; ++i) g += 1.f / (1.f + __expf(-res[192 + i]));
        gate[t] = g * (1.f / 12.f);
    }
}

// ------------------------------------------- per-head transpose: V/GV -> VT[h][64][2048]
__global__ __launch_bounds__(256) void vt_kernel(
    const __hip_bfloat16* __restrict__ qkvB, const __hip_bfloat16* __restrict__ geovB,
    __hip_bfloat16* __restrict__ VT, __hip_bfloat16* __restrict__ GVT)
{
    __shared__ __hip_bfloat16 tile[64][72];
    const int s0 = blockIdx.x << 6, h = blockIdx.y;
    const bool isGV = (blockIdx.z != 0);
    const __hip_bfloat16* src = isGV ? (geovB + h * 64) : (qkvB + 1536 + h * 64);
    const int stride = isGV ? 768 : 2304;
    __hip_bfloat16* dst = (isGV ? GVT : VT) + (size_t)h * 131072;
    const int tid = threadIdx.x;
    const int r = tid >> 2, c = (tid & 3) << 3;
    *(bf16x8*)&tile[r][c]      = *(const bf16x8*)&src[(size_t)(s0 + r) * stride + c];
    *(bf16x8*)&tile[r][c + 32] = *(const bf16x8*)&src[(size_t)(s0 + r) * stride + c + 32];
    __syncthreads();
    __hip_bfloat16 tmp[8];
    #pragma unroll
    for (int j = 0; j < 8; ++j) tmp[j] = tile[c + j][r];
    *(bf16x8*)&dst[(size_t)r * 2048 + s0 + c] = *(const bf16x8*)tmp;
    #pragma unroll
    for (int j = 0; j < 8; ++j) tmp[j] = tile[c + 32 + j][r];
    *(bf16x8*)&dst[(size_t)r * 2048 + s0 + c + 32] = *(const bf16x8*)tmp;
}

// ---------------------------------------------------------------- MFMA dual-path flash attention
// Balanced K-split (as R10/R11). LDS tiles now use the mgemm-proven 64x32
// half-tile XOR-swizzle layout (conflict-free staging + fragment reads).
// Geo path uses constant softmax max m_g = |inc_scale| (exact: lines are
// unit-norm so |geo logit| <= |isc|) -- no max-reduce / rescale chain.
__global__ __launch_bounds__(256) void mattn_kernel(
    const __hip_bfloat16* __restrict__ qkvB, const __hip_bfloat16* __restrict__ VT,
    const __hip_bfloat16* __restrict__ GVT, const __hip_bfloat16* __restrict__ rlb,
    const __hip_bfloat16* __restrict__ jwb, const float* __restrict__ gate,
    const float* __restrict__ inc_scale, __hip_bfloat16* __restrict__ comb,
    __hip_bfloat16* __restrict__ Opart, float* __restrict__ stats)
{
    __shared__ __hip_bfloat16 Ks0[2048], Ks1[2048];     // K tile: d-cols 0-31 / 32-63
    __shared__ __hip_bfloat16 VTs0[2048], VTs1[2048];   // V^T tile: s-cols 0-31 / 32-63
    __shared__ __hip_bfloat16 GVTs0[2048], GVTs1[2048];
    __shared__ __hip_bfloat16 JWs[64][8];
    __shared__ __bf16 Ps[64][72];
    __shared__ __bf16 Pg[64][72];

    const int j = 59 - blockIdx.x;
    const int hh = blockIdx.y;
    int qt, c, nc;
    if (j < 12)      { qt = j; c = 0; nc = 1; }
    else if (j < 36) { int t2 = j - 12; qt = 12 + (t2 >> 1); c = t2 & 1; nc = 2; }
    else             { int t2 = j - 36; int d3 = t2 / 3; qt = 24 + d3; c = t2 - d3 * 3; nc = 3; }
    const int q0 = qt << 6;
    const int nk = qt + 1;
    const int ktb = c * nk / nc;
    const int kte = (c + 1) * nk / nc - 1;
    const int tid = threadIdx.x;
    const int w = tid >> 6, lane = tid & 63;
    const int n = lane & 15, quad = lane >> 4;

    const int qrow = q0 + (w << 4) + n;
    const size_t qb = (size_t)qrow * 2304 + hh * 64;
    bf16x8 af0 = *(const bf16x8*)&qkvB[qb + (quad << 3)];
    bf16x8 af1 = *(const bf16x8*)&qkvB[qb + 32 + (quad << 3)];
    bf16x8 rlA = zero8();
    if (quad == 0) rlA = *(const bf16x8*)&rlb[(size_t)hh * 16384 + (size_t)qrow * 8];
    const float isc = inc_scale[hh];
    const float mgc = fabsf(isc);        // constant geo softmax max (exact bound)
    const size_t vbase = (size_t)hh * 131072;

    // staging geometry: thread covers row sRow, 16B chunk sc of each half-tile
    const int sRow = tid >> 2, sc = tid & 3;
    const int sPos = ((sc ^ ((sRow >> 1) & 3)) << 3);   // XOR-swizzled element offset
    const int sOff = sc << 3;                            // global col offset in half

    f32x4 Os[4], Og[4];
    float m_s[4], l_s[4], l_g[4];
    #pragma unroll
    for (int r = 0; r < 4; ++r) {
        m_s[r] = -1e30f; l_s[r] = 0.f; l_g[r] = 0.f;
        Os[r] = (f32x4){0.f, 0.f, 0.f, 0.f};
        Og[r] = (f32x4){0.f, 0.f, 0.f, 0.f};
    }

    // prefetch first tile into registers
    bf16x8 rK0, rK1, rV0, rV1, rG0, rG1, rJ = zero8();
    {
        const int k0 = ktb << 6;
        const size_t kb = (size_t)(k0 + sRow) * 2304 + 768 + hh * 64;
        const size_t vb = vbase + (size_t)sRow * 2048 + k0;
        rK0 = *(const bf16x8*)&qkvB[kb + sOff];
        rK1 = *(const bf16x8*)&qkvB[kb + sOff + 32];
        rV0 = *(const bf16x8*)&VT[vb + sOff];
        rV1 = *(const bf16x8*)&VT[vb + sOff + 32];
        rG0 = *(const bf16x8*)&GVT[vb + sOff];
        rG1 = *(const bf16x8*)&GVT[vb + sOff + 32];
        if (tid < 64) rJ = *(const bf16x8*)&jwb[(size_t)hh * 16384 + (size_t)(k0 + tid) * 8];
    }

    for (int kt = ktb; kt <= kte; ++kt) {
        const int k0 = kt << 6;
        __syncthreads();   // prior reads of LDS tiles done
        *(bf16x8*)&Ks0[sRow * 32 + sPos]  = rK0;
        *(bf16x8*)&Ks1[sRow * 32 + sPos]  = rK1;
        *(bf16x8*)&VTs0[sRow * 32 + sPos] = rV0;
        *(bf16x8*)&VTs1[sRow * 32 + sPos] = rV1;
        *(bf16x8*)&GVTs0[sRow * 32 + sPos] = rG0;
        *(bf16x8*)&GVTs1[sRow * 32 + sPos] = rG1;
        if (tid < 64) *(bf16x8*)&JWs[tid][0] = rJ;
        if (kt < kte) {
            const int k1 = (kt + 1) << 6;
            const size_t kb = (size_t)(k1 + sRow) * 2304 + 768 + hh * 64;
            const size_t vb = vbase + (size_t)sRow * 2048 + k1;
            rK0 = *(const bf16x8*)&qkvB[kb + sOff];
            rK1 = *(const bf16x8*)&qkvB[kb + sOff + 32];
            rV0 = *(const bf16x8*)&VT[vb + sOff];
            rV1 = *(const bf16x8*)&VT[vb + sOff + 32];
            rG0 = *(const bf16x8*)&GVT[vb + sOff];
            rG1 = *(const bf16x8*)&GVT[vb + sOff + 32];
            if (tid < 64) rJ = *(const bf16x8*)&jwb[(size_t)hh * 16384 + (size_t)(k1 + tid) * 8];
        }
        __syncthreads();   // LDS tiles ready

        // ---- S = QK^T (std) and RL·JW (geo), 4 col-tiles of 16
        f32x4 Ss[4], Sg[4];
        #pragma unroll
        for (int t = 0; t < 4; ++t) {
            Ss[t] = (f32x4){0.f, 0.f, 0.f, 0.f};
            Sg[t] = (f32x4){0.f, 0.f, 0.f, 0.f};
        }
        #pragma unroll
        for (int t = 0; t < 4; ++t) {
            const int krow = (t << 4) + n;
            const int kpos = ((quad ^ ((krow >> 1) & 3)) << 3);
            bf16x8 kb0 = *(const bf16x8*)&Ks0[krow * 32 + kpos];
            bf16x8 kb1 = *(const bf16x8*)&Ks1[krow * 32 + kpos];
            Ss[t] = __builtin_amdgcn_mfma_f32_16x16x32_bf16(af0, kb0, Ss[t], 0, 0, 0);
            Ss[t] = __builtin_amdgcn_mfma_f32_16x16x32_bf16(af1, kb1, Ss[t], 0, 0, 0);
            bf16x8 jb = zero8();
            if (quad == 0) jb = *(const bf16x8*)&JWs[krow][0];
            Sg[t] = __builtin_amdgcn_mfma_f32_16x16x32_bf16(rlA, jb, Sg[t], 0, 0, 0);
        }
        #pragma unroll
        for (int t = 0; t < 4; ++t) {
            #pragma unroll
            for (int r = 0; r < 4; ++r) { Ss[t][r] *= 0.125f; Sg[t][r] *= isc; }
        }
        if (kt == qt) {
            #pragma unroll
            for (int t = 0; t < 4; ++t) {
                const int sg = k0 + (t << 4) + n;
                #pragma unroll
                for (int r = 0; r < 4; ++r) {
                    const int qg = q0 + (w << 4) + (quad << 2) + r;
                    if (sg > qg) { Ss[t][r] = -1e30f; Sg[t][r] = -1e30f; }
                }
            }
        }

        // ---- softmax: std online; geo fixed-max (m_g = mgc, no rescale)
        #pragma unroll
        for (int r = 0; r < 4; ++r) {
            float mx = fmaxf(fmaxf(Ss[0][r], Ss[1][r]), fmaxf(Ss[2][r], Ss[3][r]));
            #pragma unroll
            for (int mk = 1; mk < 16; mk <<= 1) mx = fmaxf(mx, __shfl_xor(mx, mk));
            float mnew = fmaxf(m_s[r], mx);
            float alpha = __expf(m_s[r] - mnew);
            m_s[r] = mnew;
            float sm = 0.f;
            #pragma unroll
            for (int t = 0; t < 4; ++t) { Ss[t][r] = __expf(Ss[t][r] - mnew); sm += Ss[t][r]; }
            #pragma unroll
            for (int mk = 1; mk < 16; mk <<= 1) sm += __shfl_xor(sm, mk);
            l_s[r] = l_s[r] * alpha + sm;
            #pragma unroll
            for (int t = 0; t < 4; ++t) Os[t][r] *= alpha;

            float smg = 0.f;
            #pragma unroll
            for (int t = 0; t < 4; ++t) { Sg[t][r] = __expf(Sg[t][r] - mgc); smg += Sg[t][r]; }
            #pragma unroll
            for (int mk = 1; mk < 16; mk <<= 1) smg += __shfl_xor(smg, mk);
            l_g[r] += smg;
        }

        // ---- P -> LDS (C-layout), fence, then PV A-fragment reads
        #pragma unroll
        for (int t = 0; t < 4; ++t) {
            #pragma unroll
            for (int r = 0; r < 4; ++r) {
                Ps[(w << 4) + (quad << 2) + r][(t << 4) + n] = (__bf16)Ss[t][r];
                Pg[(w << 4) + (quad << 2) + r][(t << 4) + n] = (__bf16)Sg[t][r];
            }
        }
        __syncthreads();   // P stores visible before PV fragment loads

        // ---- PV for both paths
        #pragma unroll
        for (int st = 0; st < 2; ++st) {
            bf16x8 ap = *(const bf16x8*)&Ps[(w << 4) + n][(st << 5) + (quad << 3)];
            bf16x8 gp = *(const bf16x8*)&Pg[(w << 4) + n][(st << 5) + (quad << 3)];
            const __hip_bfloat16* Vh = st ? VTs1 : VTs0;
            const __hip_bfloat16* Gh = st ? GVTs1 : GVTs0;
            #pragma unroll
            for (int dt = 0; dt < 4; ++dt) {
                const int vrow = (dt << 4) + n;
                const int vpos = ((quad ^ ((vrow >> 1) & 3)) << 3);
                bf16x8 vb2 = *(const bf16x8*)&Vh[vrow * 32 + vpos];
                bf16x8 gb2 = *(const bf16x8*)&Gh[vrow * 32 + vpos];
                Os[dt] = __builtin_amdgcn_mfma_f32_16x16x32_bf16(ap, vb2, Os[dt], 0, 0, 0);
                Og[dt] = __builtin_amdgcn_mfma_f32_16x16x32_bf16(gp, gb2, Og[dt], 0, 0, 0);
            }
        }
    }

    if (nc == 1) {
        #pragma unroll
        for (int r = 0; r < 4; ++r) {
            const int row = q0 + (w << 4) + (quad << 2) + r;
            const float g = gate[row];
            const float invs = (1.f - g) / l_s[r], invg = g / l_g[r];
            #pragma unroll
            for (int dt = 0; dt < 4; ++dt) {
                float val = Os[dt][r] * invs + Og[dt][r] * invg;
                comb[(size_t)row * DD + hh * 64 + (dt << 4) + n] = __float2bfloat16(val);
            }
        }
    } else {
        const int base = (qt < 24) ? ((qt - 12) << 1) : (24 + (qt - 24) * 3);
        const int slot = hh * 48 + base + c;
        __hip_bfloat16* op = Opart + (size_t)slot * 8192;
        float* st = stats + (size_t)slot * 256;
        #pragma unroll
        for (int r = 0; r < 4; ++r) {
            const int rloc = (w << 4) + (quad << 2) + r;
            #pragma unroll
            for (int dt = 0; dt < 4; ++dt) {
                const int col = (dt << 4) + n;
                op[rloc * 128 + col]      = __float2bfloat16(Os[dt][r]);
                op[rloc * 128 + 64 + col] = __float2bfloat16(Og[dt][r]);
            }
            if (n == 0) {
                st[rloc * 4 + 0] = m_s[r]; st[rloc * 4 + 1] = l_s[r];
                st[rloc * 4 + 2] = mgc;    st[rloc * 4 + 3] = l_g[r];
            }
        }
    }
}

// ------------------------------------------- combine 2-3 K-chunks (qt>=12)
__global__ __launch_bounds__(256) void acomb_kernel(
    const __hip_bfloat16* __restrict__ Opart, const float* __restrict__ stats,
    const float* __restrict__ gate, __hip_bfloat16* __restrict__ comb)
{
    const int qt = 12 + blockIdx.x;
    const int h = blockIdx.y;
    const int nc = (qt < 24) ? 2 : 3;
    const int sb = h * 48 + ((qt < 24) ? ((qt - 12) << 1) : (24 + (qt - 24) * 3));
    const int tid = threadIdx.x;
    const int rloc = tid >> 2;
    const int cseg = (tid & 3) << 4;
    const int row = (qt << 6) + rloc;
    float ms = -1e30f, mg = -1e30f;
    for (int c = 0; c < nc; ++c) {
        const float* st = stats + (size_t)(sb + c) * 256 + rloc * 4;
        ms = fmaxf(ms, st[0]);
        mg = fmaxf(mg, st[2]);
    }
    float wsc[3], wgc[3];
    float ls = 0.f, lg = 0.f;
    for (int c = 0; c < nc; ++c) {
        const float* st = stats + (size_t)(sb + c) * 256 + rloc * 4;
        wsc[c] = __expf(st[0] - ms); ls += st[1] * wsc[c];
        wgc[c] = __expf(st[2] - mg); lg += st[3] * wgc[c];
    }
    const float g = gate[row];
    const float fs = (1.f - g) / ls, fg = g / lg;
    #pragma unroll
    for (int cc = 0; cc < 16; ++cc) {
        const int col = cseg + cc;
        float os = 0.f, og = 0.f;
        for (int c = 0; c < nc; ++c) {
            const __hip_bfloat16* op = Opart + (size_t)(sb + c) * 8192 + rloc * 128;
            os += __bfloat162float(op[col]) * wsc[c];
            og += __bfloat162float(op[64 + col]) * wgc[c];
        }
        comb[(size_t)row * DD + h * 64 + col] = __float2bfloat16(os * fs + og * fg);
    }
}

// ---------------------------------------------------------------- launch
extern "C" void kernel_launch(void* const* d_in, const int* in_sizes, int n_in,
                              void* d_out, int out_size, void* d_ws, size_t ws_size,
                              hipStream_t stream) {
    (void)in_sizes; (void)n_in; (void)out_size; (void)ws_size;
    const float* x      = (const float*)d_in[0];
    const float* ln1_g  = (const float*)d_in[1];
    const float* ln1_b  = (const float*)d_in[2];
    const float* qkv_w  = (const float*)d_in[3];
    const float* qkv_b  = (const float*)d_in[4];
    const float* w1w    = (const float*)d_in[5];
    const float* w2w    = (const float*)d_in[6];
    const float* w1r    = (const float*)d_in[7];
    const float* w2r    = (const float*)d_in[8];
    const float* gvw    = (const float*)d_in[9];
    const float* gvb    = (const float*)d_in[10];
    const float* gw     = (const float*)d_in[11];
    const float* gb     = (const float*)d_in[12];
    const float* isc    = (const float*)d_in[13];
    const float* ow     = (const float*)d_in[14];
    const float* ob     = (const float*)d_in[15];
    const float* ln2_g  = (const float*)d_in[16];
    const float* ln2_b  = (const float*)d_in[17];
    const float* fcw    = (const float*)d_in[18];
    const float* fcb    = (const float*)d_in[19];
    const float* pw     = (const float*)d_in[20];
    const float* pb     = (const float*)d_in[21];
    float* out = (float*)d_out;
    char* wsb  = (char*)d_ws;

    // workspace layout (bytes), total ~38.7 MB
    __hip_bfloat16* qkvB  = (__hip_bfloat16*)(wsb + 0);          //  9,437,184 bf16 [2048,2304]
    __hip_bfloat16* geovB = (__hip_bfloat16*)(wsb + 9437184);    //  3,145,728 bf16 [2048,768]
    __hip_bfloat16* VTb   = (__hip_bfloat16*)(wsb + 12582912);   //  3,145,728 bf16 [12][64][2048]
    __hip_bfloat16* GVTb  = (__hip_bfloat16*)(wsb + 15728640);   //  3,145,728
    __hip_bfloat16* rlb   = (__hip_bfloat16*)(wsb + 18874368);   //    393,216 bf16 [12][2048][8]
    __hip_bfloat16* jwb   = (__hip_bfloat16*)(wsb + 19267584);   //    393,216
    float*          gate  = (float*)(wsb + 19660800);            //      8,192
    __hip_bfloat16* ln1   = (__hip_bfloat16*)(wsb + 19668992);   //  3,145,728 (reused for ln2)
    __hip_bfloat16* comb  = (__hip_bfloat16*)(wsb + 22814720);   //  3,145,728
    float*          hbuf  = (float*)(wsb + 25960448);            //  6,291,456 fp32 [2048,768]
    __hip_bfloat16* qkvwt = (__hip_bfloat16*)(wsb + 32251904);   //  3,538,944 bf16 [2304,768]
    __hip_bfloat16* gvwt  = (__hip_bfloat16*)(wsb + 35790848);   //  1,179,648 bf16 [768,768]
    __hip_bfloat16* owt   = (__hip_bfloat16*)(wsb + 36970496);   //  1,179,648 bf16 [768,768]
    float*          stats = (float*)(wsb + 38150144);            //    589,824 fp32 [576][64][4]
    __hip_bfloat16* Opart = (__hip_bfloat16*)hbuf;               // 576 x 16KB overlay (hbuf+qkvwt dead)
    __hip_bfloat16* fcwt  = qkvwt;
    __hip_bfloat16* pwt   = (__hip_bfloat16*)(wsb + 0);
    __hip_bfloat16* fcact = (__hip_bfloat16*)(wsb + 4718592);
    float* Ppart0 = (float*)(wsb + 18874368);
    float* Ppart1 = (float*)(wsb + 32251904);

    castT_kernel<<<dim3(72, 24), 256, 0, stream>>>(qkv_w, qkvwt, 768, 2304);
    castT_kernel<<<dim3(24, 24), 256, 0, stream>>>(gvw, gvwt, 768, 768);
    ln_kernel<<<TT, 256, 0, stream>>>(x, ln1_g, ln1_b, ln1);
    mgemm64_kernel<<<dim3(18, 32, 1), 256, 0, stream>>>(ln1, qkvwt, qkv_b, nullptr, qkvB, nullptr, nullptr, TT, 2304, 768, 1, 0, 1);
    mgemm64_kernel<<<dim3(6, 32, 1), 256, 0, stream>>>(ln1, gvwt, gvb, nullptr, geovB, nullptr, nullptr, TT, 768, 768, 1, 0, 1);
    vt_kernel<<<dim3(32, 12, 2), 256, 0, stream>>>(qkvB, geovB, VTb, GVTb);
    smallproj_kernel<<<TT, 256, 0, stream>>>(ln1, w1w, w2w, w1r, w2r, gw, gb, rlb, jwb, gate);
    mattn_kernel<<<dim3(60, 12), 256, 0, stream>>>(qkvB, VTb, GVTb, rlb, jwb, gate, isc, comb, Opart, stats);
    acomb_kernel<<<dim3(20, 12), 256, 0, stream>>>(Opart, stats, gate, comb);
    castT_kernel<<<dim3(24, 24), 256, 0, stream>>>(ow, owt, 768, 768);
    mgemm64_kernel<<<dim3(6, 32, 1), 256, 0, stream>>>(comb, owt, ob, x, hbuf, nullptr, nullptr, TT, 768, 768, 1, 2, 0);
    ln_kernel<<<TT, 256, 0, stream>>>(hbuf, ln2_g, ln2_b, ln1);
    castT_kernel<<<dim3(96, 24), 256, 0, stream>>>(fcw, fcwt, 768, 3072);
    mgemm64_kernel<<<dim3(24, 32, 1), 256, 0, stream>>>(ln1, fcwt, fcb, nullptr, fcact, nullptr, nullptr, TT, 3072, 768, 1, 1, 1);
    castT_kernel<<<dim3(24, 96), 256, 0, stream>>>(pw, pwt, 3072, 768);
    mgemm64_kernel<<<dim3(6, 32, 2), 256, 0, stream>>>(fcact, pwt, pb, nullptr, nullptr, Ppart0, Ppart1, TT, 768, 3072, 2, 0, 0);
    kred_kernel<<<1536, 256, 0, stream>>>(Ppart0, Ppart1, pb, hbuf, out, 768);
}

// Round 13
// 385.391 us; speedup vs baseline: 1.3527x; 1.0426x over previous
//
#include <hip/hip_runtime.h>
#include <hip/hip_bf16.h>
#include <math.h>

#define TT 2048
#define DD 768

typedef __bf16 bf16x8 __attribute__((ext_vector_type(8)));
typedef float f32x4 __attribute__((ext_vector_type(4)));

__device__ __forceinline__ void gload16(const void* g, void* l) {
    __builtin_amdgcn_global_load_lds(
        (const __attribute__((address_space(1))) unsigned int*)g,
        (__attribute__((address_space(3))) unsigned int*)l, 16, 0, 0);
}

__device__ __forceinline__ bf16x8 zero8() {
    bf16x8 v;
    #pragma unroll
    for (int j = 0; j < 8; ++j) v[j] = (__bf16)0.0f;
    return v;
}

// ---------------------------------------------------------------- LayerNorm (fp32 in -> bf16 out)
__global__ __launch_bounds__(256) void ln_kernel(const float* __restrict__ in,
    const float* __restrict__ g, const float* __restrict__ b,
    __hip_bfloat16* __restrict__ out)
{
    const int t = blockIdx.x;
    const int tid = threadIdx.x;
    const float* row = in + (size_t)t * DD;
    float x0 = row[tid], x1 = row[tid + 256], x2 = row[tid + 512];
    float s = x0 + x1 + x2;
    float q = x0 * x0 + x1 * x1 + x2 * x2;
    #pragma unroll
    for (int m = 1; m < 64; m <<= 1) {
        s += __shfl_xor(s, m);
        q += __shfl_xor(q, m);
    }
    __shared__ float ssum[4], sqsum[4];
    const int w = tid >> 6;
    if ((tid & 63) == 0) { ssum[w] = s; sqsum[w] = q; }
    __syncthreads();
    s = ssum[0] + ssum[1] + ssum[2] + ssum[3];
    q = sqsum[0] + sqsum[1] + sqsum[2] + sqsum[3];
    const float mean = s * (1.0f / DD);
    const float var = q * (1.0f / DD) - mean * mean;
    const float rs = rsqrtf(var + 1e-5f);
    __hip_bfloat16* orow = out + (size_t)t * DD;
    orow[tid]       = __float2bfloat16((x0 - mean) * rs * g[tid]       + b[tid]);
    orow[tid + 256] = __float2bfloat16((x1 - mean) * rs * g[tid + 256] + b[tid + 256]);
    orow[tid + 512] = __float2bfloat16((x2 - mean) * rs * g[tid + 512] + b[tid + 512]);
}

// ------------------------------------------- transpose + cast: fp32 [K,N] -> bf16 [N,K]
__global__ __launch_bounds__(256) void castT_kernel(const float* __restrict__ in,
    __hip_bfloat16* __restrict__ out, int K, int N)
{
    __shared__ float t[32][33];
    const int n0 = blockIdx.x << 5, k0 = blockIdx.y << 5;
    const int tx = threadIdx.x & 31, ty = threadIdx.x >> 5;
    #pragma unroll
    for (int i = 0; i < 32; i += 8)
        t[ty + i][tx] = in[(size_t)(k0 + ty + i) * N + n0 + tx];
    __syncthreads();
    #pragma unroll
    for (int i = 0; i < 32; i += 8)
        out[(size_t)(n0 + ty + i) * K + k0 + tx] = __float2bfloat16(t[tx][ty + i]);
}

// ---------------------------------------------------------------- MFMA GEMM (64x128 tile)
__device__ __forceinline__ float gelu_f(float x) {
    float u = 0.7978845608028654f * (x + 0.044715f * x * x * x);
    return 0.5f * x * (1.0f + tanhf(u));
}

__global__ __launch_bounds__(256) void mgemm64_kernel(
    const __hip_bfloat16* __restrict__ A, const __hip_bfloat16* __restrict__ Bt,
    const float* __restrict__ bias, const float* __restrict__ resid,
    void* __restrict__ Cout, float* __restrict__ Pb0, float* __restrict__ Pb1,
    int M, int N, int K, int kz, int epi, int omode)
{
    __shared__ __hip_bfloat16 As[64 * 32];
    __shared__ __hip_bfloat16 Bs[128 * 32];
    const int tid = threadIdx.x;
    const int lane = tid & 63, w = tid >> 6;
    const int colBase = blockIdx.x << 7, rowBase = blockIdx.y << 6;
    const int z = blockIdx.z;
    const int Kc = K / kz, koff = z * Kc;

    const int lr = lane >> 2, pc = lane & 3;
    const int n = lane & 15, quad = lane >> 4;

    const int arow = (w << 4) + lr;
    const int ac = (pc ^ ((arow >> 1) & 3)) << 3;
    const int brow0 = (w << 5) + lr, brow1 = brow0 + 16;
    const int bc0 = (pc ^ ((brow0 >> 1) & 3)) << 3;
    const int bc1 = (pc ^ ((brow1 >> 1) & 3)) << 3;

    f32x4 acc[8];
    #pragma unroll
    for (int j = 0; j < 8; ++j) acc[j] = (f32x4){0.f, 0.f, 0.f, 0.f};

    const int arF = (w << 4) + n;
    const int aposF = (quad ^ ((arF >> 1) & 3)) << 3;

    for (int kk = koff; kk < koff + Kc; kk += 32) {
        __syncthreads();
        gload16(A  + (size_t)(rowBase + arow) * K + kk + ac,   &As[(w << 4) * 32]);
        gload16(Bt + (size_t)(colBase + brow0) * K + kk + bc0, &Bs[(w << 5) * 32]);
        gload16(Bt + (size_t)(colBase + brow1) * K + kk + bc1, &Bs[((w << 5) + 16) * 32]);
        __syncthreads();

        bf16x8 af = *(const bf16x8*)&As[arF * 32 + aposF];
        #pragma unroll
        for (int j = 0; j < 8; ++j) {
            const int rb = (j << 4) + n;
            bf16x8 bfj = *(const bf16x8*)&Bs[rb * 32 + ((quad ^ ((rb >> 1) & 3)) << 3)];
            acc[j] = __builtin_amdgcn_mfma_f32_16x16x32_bf16(af, bfj, acc[j], 0, 0, 0);
        }
    }

    if (kz == 1) {
        #pragma unroll
        for (int j = 0; j < 8; ++j) {
            const int col = colBase + (j << 4) + n;
            const float bj = bias[col];
            #pragma unroll
            for (int r = 0; r < 4; ++r) {
                const int row = rowBase + (w << 4) + (quad << 2) + r;
                float v = acc[j][r] + bj;
                if (epi == 1) v = gelu_f(v);
                else if (epi == 2) v += resid[(size_t)row * N + col];
                if (omode == 1) ((__hip_bfloat16*)Cout)[(size_t)row * N + col] = __float2bfloat16(v);
                else ((float*)Cout)[(size_t)row * N + col] = v;
            }
        }
    } else {
        float* P = (z == 0) ? Pb0 : Pb1;
        #pragma unroll
        for (int j = 0; j < 8; ++j) {
            const int col = colBase + (j << 4) + n;
            #pragma unroll
            for (int r = 0; r < 4; ++r) {
                const int row = rowBase + (w << 4) + (quad << 2) + r;
                P[(size_t)row * N + col] = acc[j][r];
            }
        }
    }
}

// ------------------------------------------- split-K reduce: out = p0+p1+bias+resid (fp32)
__global__ __launch_bounds__(256) void kred_kernel(
    const float* __restrict__ p0, const float* __restrict__ p1,
    const float* __restrict__ bias, const float* __restrict__ resid,
    float* __restrict__ out, int N)
{
    const int base = (blockIdx.x * 256 + threadIdx.x) << 2;
    float4 a = *(const float4*)&p0[base];
    float4 b = *(const float4*)&p1[base];
    float4 bi = *(const float4*)&bias[base % N];
    float4 rs = *(const float4*)&resid[base];
    float4 o;
    o.x = a.x + b.x + bi.x + rs.x;
    o.y = a.y + b.y + bi.y + rs.y;
    o.z = a.z + b.z + bi.z + rs.z;
    o.w = a.w + b.w + bi.w + rs.w;
    *(float4*)&out[base] = o;
}

// ------------------------------------------------- small projections + exterior
__device__ __forceinline__ void exterior6(const float* a, const float* b, float* L) {
    L[0] = a[0] * b[1] - a[1] * b[0];
    L[1] = a[0] * b[2] - a[2] * b[0];
    L[2] = a[0] * b[3] - a[3] * b[0];
    L[3] = a[1] * b[2] - a[2] * b[1];
    L[4] = a[1] * b[3] - a[3] * b[1];
    L[5] = a[2] * b[3] - a[3] * b[2];
    float n = sqrtf(L[0]*L[0] + L[1]*L[1] + L[2]*L[2] + L[3]*L[3] + L[4]*L[4] + L[5]*L[5]);
    float inv = 1.f / fmaxf(n, 1e-12f);
    #pragma unroll
    for (int p = 0; p < 6; ++p) L[p] *= inv;
}

// outputs: rlb/jwb bf16 [12][2048][8] (6 real + 2 zero pad), gate fp32 [2048]
__global__ __launch_bounds__(256) void smallproj_kernel(
    const __hip_bfloat16* __restrict__ ln1,
    const float* __restrict__ w1w, const float* __restrict__ w2w,
    const float* __restrict__ w1r, const float* __restrict__ w2r,
    const float* __restrict__ gw, const float* __restrict__ gb,
    __hip_bfloat16* __restrict__ rlb, __hip_bfloat16* __restrict__ jwb,
    float* __restrict__ gate)
{
    const int t = blockIdx.x;
    const int tid = threadIdx.x;
    __shared__ float xc[768], xp[768], res[204];
    const __hip_bfloat16* cur = ln1 + (size_t)t * DD;
    #pragma unroll
    for (int i = 0; i < 3; ++i) {
        int idx = tid + (i << 8);
        xc[idx] = __bfloat162float(cur[idx]);
        xp[idx] = (t > 0) ? __bfloat162float(cur[idx - DD]) : 0.f;
    }
    __syncthreads();
    if (tid < 204) {
        const float* wsel; const float* xv; int col, stride;
        if (tid < 48)       { wsel = w2w; xv = xc; col = tid;       stride = 48; }
        else if (tid < 96)  { wsel = w1w; xv = xp; col = tid - 48;  stride = 48; }
        else if (tid < 144) { wsel = w1r; xv = xc; col = tid - 96;  stride = 48; }
        else if (tid < 192) { wsel = w2r; xv = xc; col = tid - 144; stride = 48; }
        else                { wsel = gw;  xv = xc; col = tid - 192; stride = 12; }
        float s = 0.f;
        for (int k = 0; k < 768; ++k) s += xv[k] * wsel[(size_t)k * stride + col];
        if (tid >= 192) s += gb[col];
        res[tid] = s;
    }
    __syncthreads();
    if (tid < 12) {
        const int h = tid;
        float a[4], b[4], L[6];
        #pragma unroll
        for (int i = 0; i < 4; ++i) { a[i] = res[48 + h * 4 + i]; b[i] = res[h * 4 + i]; }
        exterior6(a, b, L);
        __hip_bfloat16* jwp = jwb + (size_t)h * 16384 + t * 8;
        jwp[0] = __float2bfloat16( L[5]); jwp[1] = __float2bfloat16(-L[4]);
        jwp[2] = __float2bfloat16( L[3]); jwp[3] = __float2bfloat16( L[2]);
        jwp[4] = __float2bfloat16(-L[1]); jwp[5] = __float2bfloat16( L[0]);
        jwp[6] = __float2bfloat16(0.f);   jwp[7] = __float2bfloat16(0.f);
        #pragma unroll
        for (int i = 0; i < 4; ++i) { a[i] = res[96 + h * 4 + i]; b[i] = res[144 + h * 4 + i]; }
        exterior6(a, b, L);
        __hip_bfloat16* rlp = rlb + (size_t)h * 16384 + t * 8;
        #pragma unroll
        for (int p = 0; p < 6; ++p) rlp[p] = __float2bfloat16(L[p]);
        rlp[6] = __float2bfloat16(0.f); rlp[7] = __float2bfloat16(0.f);
    }
    if (tid == 0) {
        float g = 0.f;
        #pragma unroll
        for (int i = 0; i < 12; ++i) g += 1.f / (1.f + __expf(-res[192 + i]));
        gate[t] = g * (1.f / 12.f);
    }
}

// ------------------------------------------- per-head transpose: V/GV -> VT[h][64][2048]
__global__ __launch_bounds__(256) void vt_kernel(
    const __hip_bfloat16* __restrict__ qkvB, const __hip_bfloat16* __restrict__ geovB,
    __hip_bfloat16* __restrict__ VT, __hip_bfloat16* __restrict__ GVT)
{
    __shared__ __hip_bfloat16 tile[64][72];
    const int s0 = blockIdx.x << 6, h = blockIdx.y;
    const bool isGV = (blockIdx.z != 0);
    const __hip_bfloat16* src = isGV ? (geovB + h * 64) : (qkvB + 1536 + h * 64);
    const int stride = isGV ? 768 : 2304;
    __hip_bfloat16* dst = (isGV ? GVT : VT) + (size_t)h * 131072;
    const int tid = threadIdx.x;
    const int r = tid >> 2, c = (tid & 3) << 3;
    *(bf16x8*)&tile[r][c]      = *(const bf16x8*)&src[(size_t)(s0 + r) * stride + c];
    *(bf16x8*)&tile[r][c + 32] = *(const bf16x8*)&src[(size_t)(s0 + r) * stride + c + 32];
    __syncthreads();
    __hip_bfloat16 tmp[8];
    #pragma unroll
    for (int j = 0; j < 8; ++j) tmp[j] = tile[c + j][r];
    *(bf16x8*)&dst[(size_t)r * 2048 + s0 + c] = *(const bf16x8*)tmp;
    #pragma unroll
    for (int j = 0; j < 8; ++j) tmp[j] = tile[c + 32 + j][r];
    *(bf16x8*)&dst[(size_t)r * 2048 + s0 + c + 32] = *(const bf16x8*)tmp;
}

// ---------------------------------------------------------------- MFMA dual-path flash attention
// Balanced K-split (R10), conflict-free half-tile layout (R12).
// R13: (1) P-fence is wave-local (s_waitcnt lgkmcnt(0)) -- P store/read touch
// only the owning wave's 16 rows; block barrier unnecessary. (2) l_s/l_g
// reductions deferred: lane-local partials (alpha is row-uniform after the
// max reduce), single shuffle-reduce after the K-loop.
__global__ __launch_bounds__(256) void mattn_kernel(
    const __hip_bfloat16* __restrict__ qkvB, const __hip_bfloat16* __restrict__ VT,
    const __hip_bfloat16* __restrict__ GVT, const __hip_bfloat16* __restrict__ rlb,
    const __hip_bfloat16* __restrict__ jwb, const float* __restrict__ gate,
    const float* __restrict__ inc_scale, __hip_bfloat16* __restrict__ comb,
    __hip_bfloat16* __restrict__ Opart, float* __restrict__ stats)
{
    __shared__ __hip_bfloat16 Ks0[2048], Ks1[2048];
    __shared__ __hip_bfloat16 VTs0[2048], VTs1[2048];
    __shared__ __hip_bfloat16 GVTs0[2048], GVTs1[2048];
    __shared__ __hip_bfloat16 JWs[64][8];
    __shared__ __bf16 Ps[64][72];
    __shared__ __bf16 Pg[64][72];

    const int j = 59 - blockIdx.x;
    const int hh = blockIdx.y;
    int qt, c, nc;
    if (j < 12)      { qt = j; c = 0; nc = 1; }
    else if (j < 36) { int t2 = j - 12; qt = 12 + (t2 >> 1); c = t2 & 1; nc = 2; }
    else             { int t2 = j - 36; int d3 = t2 / 3; qt = 24 + d3; c = t2 - d3 * 3; nc = 3; }
    const int q0 = qt << 6;
    const int nk = qt + 1;
    const int ktb = c * nk / nc;
    const int kte = (c + 1) * nk / nc - 1;
    const int tid = threadIdx.x;
    const int w = tid >> 6, lane = tid & 63;
    const int n = lane & 15, quad = lane >> 4;

    const int qrow = q0 + (w << 4) + n;
    const size_t qb = (size_t)qrow * 2304 + hh * 64;
    bf16x8 af0 = *(const bf16x8*)&qkvB[qb + (quad << 3)];
    bf16x8 af1 = *(const bf16x8*)&qkvB[qb + 32 + (quad << 3)];
    bf16x8 rlA = zero8();
    if (quad == 0) rlA = *(const bf16x8*)&rlb[(size_t)hh * 16384 + (size_t)qrow * 8];
    const float isc = inc_scale[hh];
    const float mgc = fabsf(isc);
    const size_t vbase = (size_t)hh * 131072;

    const int sRow = tid >> 2, sc = tid & 3;
    const int sPos = ((sc ^ ((sRow >> 1) & 3)) << 3);
    const int sOff = sc << 3;

    f32x4 Os[4], Og[4];
    float m_s[4], lsp[4], lgp[4];      // lane-local partial sums
    #pragma unroll
    for (int r = 0; r < 4; ++r) {
        m_s[r] = -1e30f; lsp[r] = 0.f; lgp[r] = 0.f;
        Os[r] = (f32x4){0.f, 0.f, 0.f, 0.f};
        Og[r] = (f32x4){0.f, 0.f, 0.f, 0.f};
    }

    bf16x8 rK0, rK1, rV0, rV1, rG0, rG1, rJ = zero8();
    {
        const int k0 = ktb << 6;
        const size_t kb = (size_t)(k0 + sRow) * 2304 + 768 + hh * 64;
        const size_t vb = vbase + (size_t)sRow * 2048 + k0;
        rK0 = *(const bf16x8*)&qkvB[kb + sOff];
        rK1 = *(const bf16x8*)&qkvB[kb + sOff + 32];
        rV0 = *(const bf16x8*)&VT[vb + sOff];
        rV1 = *(const bf16x8*)&VT[vb + sOff + 32];
        rG0 = *(const bf16x8*)&GVT[vb + sOff];
        rG1 = *(const bf16x8*)&GVT[vb + sOff + 32];
        if (tid < 64) rJ = *(const bf16x8*)&jwb[(size_t)hh * 16384 + (size_t)(k0 + tid) * 8];
    }

    for (int kt = ktb; kt <= kte; ++kt) {
        const int k0 = kt << 6;
        __syncthreads();   // prior reads of LDS tiles done
        *(bf16x8*)&Ks0[sRow * 32 + sPos]  = rK0;
        *(bf16x8*)&Ks1[sRow * 32 + sPos]  = rK1;
        *(bf16x8*)&VTs0[sRow * 32 + sPos] = rV0;
        *(bf16x8*)&VTs1[sRow * 32 + sPos] = rV1;
        *(bf16x8*)&GVTs0[sRow * 32 + sPos] = rG0;
        *(bf16x8*)&GVTs1[sRow * 32 + sPos] = rG1;
        if (tid < 64) *(bf16x8*)&JWs[tid][0] = rJ;
        if (kt < kte) {
            const int k1 = (kt + 1) << 6;
            const size_t kb = (size_t)(k1 + sRow) * 2304 + 768 + hh * 64;
            const size_t vb = vbase + (size_t)sRow * 2048 + k1;
            rK0 = *(const bf16x8*)&qkvB[kb + sOff];
            rK1 = *(const bf16x8*)&qkvB[kb + sOff + 32];
            rV0 = *(const bf16x8*)&VT[vb + sOff];
            rV1 = *(const bf16x8*)&VT[vb + sOff + 32];
            rG0 = *(const bf16x8*)&GVT[vb + sOff];
            rG1 = *(const bf16x8*)&GVT[vb + sOff + 32];
            if (tid < 64) rJ = *(const bf16x8*)&jwb[(size_t)hh * 16384 + (size_t)(k1 + tid) * 8];
        }
        __syncthreads();   // LDS tiles ready

        // ---- S = QK^T (std) and RL·JW (geo)
        f32x4 Ss[4], Sg[4];
        #pragma unroll
        for (int t = 0; t < 4; ++t) {
            Ss[t] = (f32x4){0.f, 0.f, 0.f, 0.f};
            Sg[t] = (f32x4){0.f, 0.f, 0.f, 0.f};
        }
        #pragma unroll
        for (int t = 0; t < 4; ++t) {
            const int krow = (t << 4) + n;
            const int kpos = ((quad ^ ((krow >> 1) & 3)) << 3);
            bf16x8 kb0 = *(const bf16x8*)&Ks0[krow * 32 + kpos];
            bf16x8 kb1 = *(const bf16x8*)&Ks1[krow * 32 + kpos];
            Ss[t] = __builtin_amdgcn_mfma_f32_16x16x32_bf16(af0, kb0, Ss[t], 0, 0, 0);
            Ss[t] = __builtin_amdgcn_mfma_f32_16x16x32_bf16(af1, kb1, Ss[t], 0, 0, 0);
            bf16x8 jb = zero8();
            if (quad == 0) jb = *(const bf16x8*)&JWs[krow][0];
            Sg[t] = __builtin_amdgcn_mfma_f32_16x16x32_bf16(rlA, jb, Sg[t], 0, 0, 0);
        }
        #pragma unroll
        for (int t = 0; t < 4; ++t) {
            #pragma unroll
            for (int r = 0; r < 4; ++r) { Ss[t][r] *= 0.125f; Sg[t][r] *= isc; }
        }
        if (kt == qt) {
            #pragma unroll
            for (int t = 0; t < 4; ++t) {
                const int sg = k0 + (t << 4) + n;
                #pragma unroll
                for (int r = 0; r < 4; ++r) {
                    const int qg = q0 + (w << 4) + (quad << 2) + r;
                    if (sg > qg) { Ss[t][r] = -1e30f; Sg[t][r] = -1e30f; }
                }
            }
        }

        // ---- softmax: std max-reduce only; sums kept lane-local
        #pragma unroll
        for (int r = 0; r < 4; ++r) {
            float mx = fmaxf(fmaxf(Ss[0][r], Ss[1][r]), fmaxf(Ss[2][r], Ss[3][r]));
            #pragma unroll
            for (int mk = 1; mk < 16; mk <<= 1) mx = fmaxf(mx, __shfl_xor(mx, mk));
            float mnew = fmaxf(m_s[r], mx);
            float alpha = __expf(m_s[r] - mnew);   // row-uniform
            m_s[r] = mnew;
            float sm = 0.f;
            #pragma unroll
            for (int t = 0; t < 4; ++t) { Ss[t][r] = __expf(Ss[t][r] - mnew); sm += Ss[t][r]; }
            lsp[r] = lsp[r] * alpha + sm;
            #pragma unroll
            for (int t = 0; t < 4; ++t) Os[t][r] *= alpha;

            float smg = 0.f;
            #pragma unroll
            for (int t = 0; t < 4; ++t) { Sg[t][r] = __expf(Sg[t][r] - mgc); smg += Sg[t][r]; }
            lgp[r] += smg;
        }

        // ---- P -> LDS (same-wave rows only), wave-local fence, PV reads
        #pragma unroll
        for (int t = 0; t < 4; ++t) {
            #pragma unroll
            for (int r = 0; r < 4; ++r) {
                Ps[(w << 4) + (quad << 2) + r][(t << 4) + n] = (__bf16)Ss[t][r];
                Pg[(w << 4) + (quad << 2) + r][(t << 4) + n] = (__bf16)Sg[t][r];
            }
        }
        asm volatile("s_waitcnt lgkmcnt(0)" ::: "memory");  // wave-local P fence

        // ---- PV for both paths
        #pragma unroll
        for (int st = 0; st < 2; ++st) {
            bf16x8 ap = *(const bf16x8*)&Ps[(w << 4) + n][(st << 5) + (quad << 3)];
            bf16x8 gp = *(const bf16x8*)&Pg[(w << 4) + n][(st << 5) + (quad << 3)];
            const __hip_bfloat16* Vh = st ? VTs1 : VTs0;
            const __hip_bfloat16* Gh = st ? GVTs1 : GVTs0;
            #pragma unroll
            for (int dt = 0; dt < 4; ++dt) {
                const int vrow = (dt << 4) + n;
                const int vpos = ((quad ^ ((vrow >> 1) & 3)) << 3);
                bf16x8 vb2 = *(const bf16x8*)&Vh[vrow * 32 + vpos];
                bf16x8 gb2 = *(const bf16x8*)&Gh[vrow * 32 + vpos];
                Os[dt] = __builtin_amdgcn_mfma_f32_16x16x32_bf16(ap, vb2, Os[dt], 0, 0, 0);
                Og[dt] = __builtin_amdgcn_mfma_f32_16x16x32_bf16(gp, gb2, Og[dt], 0, 0, 0);
            }
        }
    }

    // ---- final l_s / l_g reduction (once, not per iteration)
    float l_s[4], l_g[4];
    #pragma unroll
    for (int r = 0; r < 4; ++r) {
        float ls = lsp[r], lg = lgp[r];
        #pragma unroll
        for (int mk = 1; mk < 16; mk <<= 1) {
            ls += __shfl_xor(ls, mk);
            lg += __shfl_xor(lg, mk);
        }
        l_s[r] = ls; l_g[r] = lg;
    }

    if (nc == 1) {
        #pragma unroll
        for (int r = 0; r < 4; ++r) {
            const int row = q0 + (w << 4) + (quad << 2) + r;
            const float g = gate[row];
            const float invs = (1.f - g) / l_s[r], invg = g / l_g[r];
            #pragma unroll
            for (int dt = 0; dt < 4; ++dt) {
                float val = Os[dt][r] * invs + Og[dt][r] * invg;
                comb[(size_t)row * DD + hh * 64 + (dt << 4) + n] = __float2bfloat16(val);
            }
        }
    } else {
        const int base = (qt < 24) ? ((qt - 12) << 1) : (24 + (qt - 24) * 3);
        const int slot = hh * 48 + base + c;
        __hip_bfloat16* op = Opart + (size_t)slot * 8192;
        float* st = stats + (size_t)slot * 256;
        #pragma unroll
        for (int r = 0; r < 4; ++r) {
            const int rloc = (w << 4) + (quad << 2) + r;
            #pragma unroll
            for (int dt = 0; dt < 4; ++dt) {
                const int col = (dt << 4) + n;
                op[rloc * 128 + col]      = __float2bfloat16(Os[dt][r]);
                op[rloc * 128 + 64 + col] = __float2bfloat16(Og[dt][r]);
            }
            if (n == 0) {
                st[rloc * 4 + 0] = m_s[r]; st[rloc * 4 + 1] = l_s[r];
                st[rloc * 4 + 2] = mgc;    st[rloc * 4 + 3] = l_g[r];
            }
        }
    }
}

// ------------------------------------------- combine 2-3 K-chunks (qt>=12)
__global__ __launch_bounds__(256) void acomb_kernel(
    const __hip_bfloat16* __restrict__ Opart, const float* __restrict__ stats,
    const float* __restrict__ gate, __hip_bfloat16* __restrict__ comb)
{
    const int qt = 12 + blockIdx.x;
    const int h = blockIdx.y;
    const int nc = (qt < 24) ? 2 : 3;
    const int sb = h * 48 + ((qt < 24) ? ((qt - 12) << 1) : (24 + (qt - 24) * 3));
    const int tid = threadIdx.x;
    const int rloc = tid >> 2;
    const int cseg = (tid & 3) << 4;
    const int row = (qt << 6) + rloc;
    float ms = -1e30f, mg = -1e30f;
    for (int c = 0; c < nc; ++c) {
        const float* st = stats + (size_t)(sb + c) * 256 + rloc * 4;
        ms = fmaxf(ms, st[0]);
        mg = fmaxf(mg, st[2]);
    }
    float wsc[3], wgc[3];
    float ls = 0.f, lg = 0.f;
    for (int c = 0; c < nc; ++c) {
        const float* st = stats + (size_t)(sb + c) * 256 + rloc * 4;
        wsc[c] = __expf(st[0] - ms); ls += st[1] * wsc[c];
        wgc[c] = __expf(st[2] - mg); lg += st[3] * wgc[c];
    }
    const float g = gate[row];
    const float fs = (1.f - g) / ls, fg = g / lg;
    #pragma unroll
    for (int cc = 0; cc < 16; ++cc) {
        const int col = cseg + cc;
        float os = 0.f, og = 0.f;
        for (int c = 0; c < nc; ++c) {
            const __hip_bfloat16* op = Opart + (size_t)(sb + c) * 8192 + rloc * 128;
            os += __bfloat162float(op[col]) * wsc[c];
            og += __bfloat162float(op[64 + col]) * wgc[c];
        }
        comb[(size_t)row * DD + h * 64 + col] = __float2bfloat16(os * fs + og * fg);
    }
}

// ---------------------------------------------------------------- launch
extern "C" void kernel_launch(void* const* d_in, const int* in_sizes, int n_in,
                              void* d_out, int out_size, void* d_ws, size_t ws_size,
                              hipStream_t stream) {
    (void)in_sizes; (void)n_in; (void)out_size; (void)ws_size;
    const float* x      = (const float*)d_in[0];
    const float* ln1_g  = (const float*)d_in[1];
    const float* ln1_b  = (const float*)d_in[2];
    const float* qkv_w  = (const float*)d_in[3];
    const float* qkv_b  = (const float*)d_in[4];
    const float* w1w    = (const float*)d_in[5];
    const float* w2w    = (const float*)d_in[6];
    const float* w1r    = (const float*)d_in[7];
    const float* w2r    = (const float*)d_in[8];
    const float* gvw    = (const float*)d_in[9];
    const float* gvb    = (const float*)d_in[10];
    const float* gw     = (const float*)d_in[11];
    const float* gb     = (const float*)d_in[12];
    const float* isc    = (const float*)d_in[13];
    const float* ow     = (const float*)d_in[14];
    const float* ob     = (const float*)d_in[15];
    const float* ln2_g  = (const float*)d_in[16];
    const float* ln2_b  = (const float*)d_in[17];
    const float* fcw    = (const float*)d_in[18];
    const float* fcb    = (const float*)d_in[19];
    const float* pw     = (const float*)d_in[20];
    const float* pb     = (const float*)d_in[21];
    float* out = (float*)d_out;
    char* wsb  = (char*)d_ws;

    __hip_bfloat16* qkvB  = (__hip_bfloat16*)(wsb + 0);
    __hip_bfloat16* geovB = (__hip_bfloat16*)(wsb + 9437184);
    __hip_bfloat16* VTb   = (__hip_bfloat16*)(wsb + 12582912);
    __hip_bfloat16* GVTb  = (__hip_bfloat16*)(wsb + 15728640);
    __hip_bfloat16* rlb   = (__hip_bfloat16*)(wsb + 18874368);
    __hip_bfloat16* jwb   = (__hip_bfloat16*)(wsb + 19267584);
    float*          gate  = (float*)(wsb + 19660800);
    __hip_bfloat16* ln1   = (__hip_bfloat16*)(wsb + 19668992);
    __hip_bfloat16* comb  = (__hip_bfloat16*)(wsb + 22814720);
    float*          hbuf  = (float*)(wsb + 25960448);
    __hip_bfloat16* qkvwt = (__hip_bfloat16*)(wsb + 32251904);
    __hip_bfloat16* gvwt  = (__hip_bfloat16*)(wsb + 35790848);
    __hip_bfloat16* owt   = (__hip_bfloat16*)(wsb + 36970496);
    float*          stats = (float*)(wsb + 38150144);
    __hip_bfloat16* Opart = (__hip_bfloat16*)hbuf;
    __hip_bfloat16* fcwt  = qkvwt;
    __hip_bfloat16* pwt   = (__hip_bfloat16*)(wsb + 0);
    __hip_bfloat16* fcact = (__hip_bfloat16*)(wsb + 4718592);
    float* Ppart0 = (float*)(wsb + 18874368);
    float* Ppart1 = (float*)(wsb + 32251904);

    castT_kernel<<<dim3(72, 24), 256, 0, stream>>>(qkv_w, qkvwt, 768, 2304);
    castT_kernel<<<dim3(24, 24), 256, 0, stream>>>(gvw, gvwt, 768, 768);
    ln_kernel<<<TT, 256, 0, stream>>>(x, ln1_g, ln1_b, ln1);
    mgemm64_kernel<<<dim3(18, 32, 1), 256, 0, stream>>>(ln1, qkvwt, qkv_b, nullptr, qkvB, nullptr, nullptr, TT, 2304, 768, 1, 0, 1);
    mgemm64_kernel<<<dim3(6, 32, 1), 256, 0, stream>>>(ln1, gvwt, gvb, nullptr, geovB, nullptr, nullptr, TT, 768, 768, 1, 0, 1);
    vt_kernel<<<dim3(32, 12, 2), 256, 0, stream>>>(qkvB, geovB, VTb, GVTb);
    smallproj_kernel<<<TT, 256, 0, stream>>>(ln1, w1w, w2w, w1r, w2r, gw, gb, rlb, jwb, gate);
    mattn_kernel<<<dim3(60, 12), 256, 0, stream>>>(qkvB, VTb, GVTb, rlb, jwb, gate, isc, comb, Opart, stats);
    acomb_kernel<<<dim3(20, 12), 256, 0, stream>>>(Opart, stats, gate, comb);
    castT_kernel<<<dim3(24, 24), 256, 0, stream>>>(ow, owt, 768, 768);
    mgemm64_kernel<<<dim3(6, 32, 1), 256, 0, stream>>>(comb, owt, ob, x, hbuf, nullptr, nullptr, TT, 768, 768, 1, 2, 0);
    ln_kernel<<<TT, 256, 0, stream>>>(hbuf, ln2_g, ln2_b, ln1);
    castT_kernel<<<dim3(96, 24), 256, 0, stream>>>(fcw, fcwt, 768, 3072);
    mgemm64_kernel<<<dim3(24, 32, 1), 256, 0, stream>>>(ln1, fcwt, fcb, nullptr, fcact, nullptr, nullptr, TT, 3072, 768, 1, 1, 1);
    castT_kernel<<<dim3(24, 96), 256, 0, stream>>>(pw, pwt, 3072, 768);
    mgemm64_kernel<<<dim3(6, 32, 2), 256, 0, stream>>>(fcact, pwt, pb, nullptr, nullptr, Ppart0, Ppart1, TT, 768, 3072, 2, 0, 0);
    kred_kernel<<<1536, 256, 0, stream>>>(Ppart0, Ppart1, pb, hbuf, out, 768);
}